// Round 6
// baseline (1688.221 us; speedup 1.0000x reference)
//
#include <hip/hip_runtime.h>

#define N_NODES 100000
#define N_EDGES 1600000
#define NB 1563            // ceil(100000/64) buckets of 64 dst nodes
// IN=128, HID=128, OUT=2

__device__ __forceinline__ int clamp_idx(int v) {
  return v < 0 ? 0 : (v >= N_NODES ? N_NODES - 1 : v);
}

__device__ __forceinline__ unsigned short f2bf(float f) {
  unsigned u = __float_as_uint(f);
  unsigned r = ((u >> 16) & 1u) + 0x7fffu;  // round-to-nearest-even
  return (unsigned short)((u + r) >> 16);
}
__device__ __forceinline__ float bf_lo(unsigned u) { return __uint_as_float(u << 16); }
__device__ __forceinline__ float bf_hi(unsigned u) { return __uint_as_float(u & 0xffff0000u); }

// ---------------- degree count ----------------

__global__ __launch_bounds__(256) void count_kernel(const int* __restrict__ dst,
                                                    int* __restrict__ counts) {
  int e = blockIdx.x * 256 + threadIdx.x;
  if (e < N_EDGES) atomicAdd(&counts[clamp_idx(dst[e])], 1);
}

// ---------------- per-node dis + per-bucket offsets (order-free reservation) ----
// Wave per bucket: lane -> node. 391 blocks x 4 waves.
__global__ __launch_bounds__(256) void bucket_kernel(const int* __restrict__ counts,
                                                     float* __restrict__ dis,
                                                     int* __restrict__ bucket_start,
                                                     int* __restrict__ bucket_cnt,
                                                     int* __restrict__ cursor,
                                                     int* __restrict__ total) {
  int wb = blockIdx.x * 4 + (threadIdx.x >> 6);
  if (wb >= NB) return;
  int lane = threadIdx.x & 63;
  int n = wb * 64 + lane;
  int c = 0;
  if (n < N_NODES) {
    c = counts[n];
    dis[n] = rsqrtf((float)c + 1.0f);
  }
#pragma unroll
  for (int off = 32; off >= 1; off >>= 1) c += __shfl_xor(c, off);
  if (lane == 0) {
    int st = atomicAdd(total, c);
    bucket_start[wb] = st;
    bucket_cnt[wb] = c;
    cursor[wb] = st;
  }
}

// ---------------- bucketed scatter: {src | ldst<<20, norm} ----------------
__global__ __launch_bounds__(256) void scatter_bucket(const int* __restrict__ src,
                                                      const int* __restrict__ dst,
                                                      const float* __restrict__ dis,
                                                      int* __restrict__ cursor,
                                                      int2* __restrict__ erec) {
  int e = blockIdx.x * 256 + threadIdx.x;
  if (e < N_EDGES) {
    int s = clamp_idx(src[e]), d = clamp_idx(dst[e]);
    int b = d >> 6;
    int pos = atomicAdd(&cursor[b], 1);
    if (pos >= 0 && pos < N_EDGES) {
      erec[pos] = make_int2(s | ((d & 63) << 20), __float_as_int(dis[s] * dis[d]));
    }
  }
}

// ---------------- GEMM: xwb = bf16(x @ W1) ----------------
// Block 256 -> 32 rows x 128 cols, thread = 4 rows x 4 cols. Row = 64 uints.
__global__ __launch_bounds__(256) void gemm_xw(const float* __restrict__ x,
                                               const float* __restrict__ Wg,
                                               unsigned int* __restrict__ xwb) {
  __shared__ float Wl[32 * 128];
  __shared__ float Xlt[32 * 36];
  int t = threadIdx.x;
  int r0 = blockIdx.x * 32;        // 100000 = 32 * 3125 exactly
  int tx = t & 31, ty = t >> 5;
  float acc[4][4] = {};

  for (int kb = 0; kb < 4; ++kb) {
    __syncthreads();
#pragma unroll
    for (int i = 0; i < 4; ++i) {
      int f = (i * 256 + t) * 4;
      *(float4*)&Wl[f] = *(const float4*)&Wg[kb * 32 * 128 + f];
    }
    {
      int row = t >> 3, kk = (t & 7) * 4;
      float4 v = *(const float4*)&x[(r0 + row) * 128 + kb * 32 + kk];
      Xlt[(kk + 0) * 36 + row] = v.x;
      Xlt[(kk + 1) * 36 + row] = v.y;
      Xlt[(kk + 2) * 36 + row] = v.z;
      Xlt[(kk + 3) * 36 + row] = v.w;
    }
    __syncthreads();
#pragma unroll
    for (int k = 0; k < 32; ++k) {
      float4 wv = *(float4*)&Wl[k * 128 + tx * 4];
      float4 xv = *(float4*)&Xlt[k * 36 + ty * 4];
      float xr[4] = {xv.x, xv.y, xv.z, xv.w};
#pragma unroll
      for (int i = 0; i < 4; ++i) {
        acc[i][0] += xr[i] * wv.x;
        acc[i][1] += xr[i] * wv.y;
        acc[i][2] += xr[i] * wv.z;
        acc[i][3] += xr[i] * wv.w;
      }
    }
  }
#pragma unroll
  for (int i = 0; i < 4; ++i) {
    unsigned lo = ((unsigned)f2bf(acc[i][1]) << 16) | f2bf(acc[i][0]);
    unsigned hi = ((unsigned)f2bf(acc[i][3]) << 16) | f2bf(acc[i][2]);
    int row = r0 + ty * 4 + i;
    *(uint2*)&xwb[row * 64 + tx * 2] = make_uint2(lo, hi);
  }
}

// ---------------- Layer-1: bucketed LDS-accumulate + fused (h @ W2) ----------------
// One workgroup per bucket. acc[64 nodes][128 ch] fp32 in LDS (32 KB).
// Lane l owns channels {l, l+64}: LDS addrs ld*128+l and ld*128+64+l -> perfect
// 2-way bank pattern (free). Per edge: wave reads 256B row of xwb[src] as 2x128B.
__global__ __launch_bounds__(256) void agg1_bucket(const unsigned int* __restrict__ xwb,
                                                   const float* __restrict__ b1,
                                                   const float* __restrict__ W2,
                                                   const float* __restrict__ dis,
                                                   const int* __restrict__ bucket_start,
                                                   const int* __restrict__ bucket_cnt,
                                                   const int2* __restrict__ erec,
                                                   float* __restrict__ hw) {
  __shared__ float acc[64 * 128];  // 32 KB
  int b = blockIdx.x;
  int t = threadIdx.x;
  int wv = t >> 6, lane = t & 63;

  // zero accum (2048 float4 / 256 threads = 8 iters)
#pragma unroll
  for (int i = 0; i < 8; ++i) {
    *(float4*)&acc[(i * 256 + t) * 4] = make_float4(0.f, 0.f, 0.f, 0.f);
  }
  __syncthreads();

  int start = bucket_start[b];
  int cnt = bucket_cnt[b];
  int uidx = lane >> 1;            // uint index for ch 'lane' (half = lane&1)

  // wave-strided edges, 2-deep (edges i and i+4 in flight)
  for (int i = wv; i < cnt; i += 8) {
    int2 e0 = erec[start + i];
    bool v1 = (i + 4) < cnt;
    int2 e1 = erec[start + (v1 ? (i + 4) : i)];
    int s0 = e0.x & 0xFFFFF, ld0 = e0.x >> 20;
    float n0 = __int_as_float(e0.y);
    unsigned u0a = xwb[s0 * 64 + uidx];
    unsigned u0b = xwb[s0 * 64 + 32 + uidx];
    int s1 = e1.x & 0xFFFFF, ld1 = e1.x >> 20;
    float n1 = __int_as_float(e1.y);
    unsigned u1a = xwb[s1 * 64 + uidx];
    unsigned u1b = xwb[s1 * 64 + 32 + uidx];
    float f0a = (lane & 1) ? bf_hi(u0a) : bf_lo(u0a);
    float f0b = (lane & 1) ? bf_hi(u0b) : bf_lo(u0b);
    atomicAdd(&acc[ld0 * 128 + lane], f0a * n0);
    atomicAdd(&acc[ld0 * 128 + 64 + lane], f0b * n0);
    if (v1) {  // uniform per wave
      float f1a = (lane & 1) ? bf_hi(u1a) : bf_lo(u1a);
      float f1b = (lane & 1) ? bf_hi(u1b) : bf_lo(u1b);
      atomicAdd(&acc[ld1 * 128 + lane], f1a * n1);
      atomicAdd(&acc[ld1 * 128 + 64 + lane], f1b * n1);
    }
  }
  __syncthreads();

  // epilogue: 16 nodes per wave
  int node0 = b * 64;
  float2 w0 = *(const float2*)&W2[lane * 2];         // W2 row 'lane'
  float2 w1 = *(const float2*)&W2[(64 + lane) * 2];  // W2 row 'lane+64'
  float bia = b1[lane], bib = b1[64 + lane];
  for (int k = 0; k < 16; ++k) {
    int ld = wv * 16 + k;
    int n = node0 + ld;
    if (n >= N_NODES) break;  // uniform within wave
    float a0 = acc[ld * 128 + lane];
    float a1 = acc[ld * 128 + 64 + lane];
    unsigned ua = xwb[n * 64 + uidx];
    unsigned ub = xwb[n * 64 + 32 + uidx];
    float sa = (lane & 1) ? bf_hi(ua) : bf_lo(ua);
    float sb = (lane & 1) ? bf_hi(ub) : bf_lo(ub);
    float ds = dis[n];
    float dsq = ds * ds;
    a0 = fmaxf(a0 + sa * dsq + bia, 0.f);
    a1 = fmaxf(a1 + sb * dsq + bib, 0.f);
    float p0 = a0 * w0.x + a1 * w1.x;
    float p1 = a0 * w0.y + a1 * w1.y;
#pragma unroll
    for (int off = 32; off >= 1; off >>= 1) {
      p0 += __shfl_xor(p0, off);
      p1 += __shfl_xor(p1, off);
    }
    if (lane == 0) *(float2*)&hw[n * 2] = make_float2(p0, p1);
  }
}

// ---------------- Layer-2: bucketed LDS-accumulate (2 channels) ----------------
__global__ __launch_bounds__(256) void agg2_bucket(const float* __restrict__ hw,
                                                   const float* __restrict__ b2,
                                                   const float* __restrict__ dis,
                                                   const int* __restrict__ bucket_start,
                                                   const int* __restrict__ bucket_cnt,
                                                   const int2* __restrict__ erec,
                                                   float* __restrict__ out) {
  __shared__ float acc2[64 * 2];
  int b = blockIdx.x;
  int t = threadIdx.x;
  if (t < 128) acc2[t] = 0.f;
  __syncthreads();
  int start = bucket_start[b];
  int cnt = bucket_cnt[b];
  for (int i = t; i < cnt; i += 256) {
    int2 e = erec[start + i];
    int s = e.x & 0xFFFFF, ld = e.x >> 20;
    float n = __int_as_float(e.y);
    float2 v = *(const float2*)&hw[s * 2];
    atomicAdd(&acc2[ld * 2], v.x * n);
    atomicAdd(&acc2[ld * 2 + 1], v.y * n);
  }
  __syncthreads();
  if (t < 64) {
    int n = b * 64 + t;
    if (n < N_NODES) {
      float ds = dis[n];
      float dsq = ds * ds;
      float2 v = *(const float2*)&hw[n * 2];
      out[n * 2 + 0] = acc2[t * 2] + v.x * dsq + b2[0];
      out[n * 2 + 1] = acc2[t * 2 + 1] + v.y * dsq + b2[1];
    }
  }
}

// ---------------- launch ----------------

extern "C" void kernel_launch(void* const* d_in, const int* in_sizes, int n_in,
                              void* d_out, int out_size, void* d_ws, size_t ws_size,
                              hipStream_t stream) {
  const float* x  = (const float*)d_in[0];
  const int*   ei = (const int*)d_in[1];
  const float* W1 = (const float*)d_in[2];
  const float* b1 = (const float*)d_in[3];
  const float* W2 = (const float*)d_in[4];
  const float* b2 = (const float*)d_in[5];
  float* out = (float*)d_out;

  const int* src = ei;            // edge_index[0]
  const int* dst = ei + N_EDGES;  // edge_index[1]

  char* ws = (char*)d_ws;
  size_t off = 0;
  auto walloc = [&](size_t bytes) -> void* {
    void* p = ws + off;
    off += (bytes + 255) & ~(size_t)255;
    return p;
  };
  unsigned int* xwb  = (unsigned int*)walloc((size_t)N_NODES * 128 * 2);  // 25.6 MB bf16
  int*   counts       = (int*)walloc((size_t)N_NODES * 4);
  float* dis          = (float*)walloc((size_t)N_NODES * 4);
  int*   bucket_start = (int*)walloc((size_t)NB * 4);
  int*   bucket_cnt   = (int*)walloc((size_t)NB * 4);
  int*   cursor       = (int*)walloc((size_t)NB * 4);
  int*   total        = (int*)walloc(256);
  int2*  erec         = (int2*)walloc((size_t)N_EDGES * 8);               // 12.8 MB
  float* hw           = (float*)walloc((size_t)N_NODES * 2 * 4);

  if (off > ws_size) return;  // workspace too small: fail visibly, don't corrupt memory

  hipMemsetAsync(counts, 0, (size_t)N_NODES * 4, stream);
  hipMemsetAsync(total, 0, 4, stream);

  count_kernel<<<(N_EDGES + 255) / 256, 256, 0, stream>>>(dst, counts);
  bucket_kernel<<<(NB + 3) / 4, 256, 0, stream>>>(counts, dis, bucket_start, bucket_cnt,
                                                  cursor, total);
  scatter_bucket<<<(N_EDGES + 255) / 256, 256, 0, stream>>>(src, dst, dis, cursor, erec);
  gemm_xw<<<N_NODES / 32, 256, 0, stream>>>(x, W1, xwb);
  agg1_bucket<<<NB, 256, 0, stream>>>(xwb, b1, W2, dis, bucket_start, bucket_cnt, erec, hw);
  agg2_bucket<<<NB, 256, 0, stream>>>(hw, b2, dis, bucket_start, bucket_cnt, erec, out);
}

// Round 7
// 536.610 us; speedup vs baseline: 3.1461x; 3.1461x over previous
//
#include <hip/hip_runtime.h>

#define N_NODES 100000
#define N_EDGES 1600000
#define NB 1563            // ceil(100000/64) buckets of 64 dst nodes
#define CAP 2048           // per-bucket record capacity (mean 1024, +32 sigma)
// IN=128, HID=128, OUT=2

__device__ __forceinline__ int clamp_idx(int v) {
  return v < 0 ? 0 : (v >= N_NODES ? N_NODES - 1 : v);
}

__device__ __forceinline__ unsigned short f2bf(float f) {
  unsigned u = __float_as_uint(f);
  unsigned r = ((u >> 16) & 1u) + 0x7fffu;  // round-to-nearest-even
  return (unsigned short)((u + r) >> 16);
}
__device__ __forceinline__ float bf_lo(unsigned u) { return __uint_as_float(u << 16); }
__device__ __forceinline__ float bf_hi(unsigned u) { return __uint_as_float(u & 0xffff0000u); }

// ---------------- bucketed scatter: 4B record {src | ldst<<20} ----------------
// Write frontier = 1563 active lines (~100 KB) -> L2-resident, lines fill.
__global__ __launch_bounds__(256) void scatter_bucket(const int* __restrict__ src,
                                                      const int* __restrict__ dst,
                                                      int* __restrict__ cursor,
                                                      int* __restrict__ eraw) {
  int e = blockIdx.x * 256 + threadIdx.x;
  if (e < N_EDGES) {
    int s = clamp_idx(src[e]), d = clamp_idx(dst[e]);
    int b = d >> 6;
    int pos = atomicAdd(&cursor[b], 1);
    if (pos < CAP) eraw[b * CAP + pos] = s | ((d & 63) << 20);
  }
}

// ---------------- per-bucket LDS counting sort -> node-sorted CSR ----------------
// Block per bucket. Also emits per-node counts, row_start, deg_inv_sqrt.
__global__ __launch_bounds__(256) void bucket_sort(const int* __restrict__ cursor,
                                                   const int* __restrict__ eraw,
                                                   int* __restrict__ esrt,
                                                   int* __restrict__ row_start,
                                                   int* __restrict__ counts,
                                                   float* __restrict__ dis) {
  __shared__ int hist[64];
  __shared__ int lcur[64];
  int b = blockIdx.x;
  int t = threadIdx.x;
  int cnt = cursor[b];
  cnt = cnt > CAP ? CAP : cnt;
  if (t < 64) hist[t] = 0;
  __syncthreads();
  for (int i = t; i < cnt; i += 256) {
    atomicAdd(&hist[(eraw[b * CAP + i] >> 20) & 63], 1);
  }
  __syncthreads();
  if (t < 64) {  // thread 0..63 = wave 0: 64-wide exclusive scan via shfl
    int v = hist[t];
    int x = v;
#pragma unroll
    for (int dlt = 1; dlt < 64; dlt <<= 1) {
      int y = __shfl_up(x, dlt);
      if (t >= dlt) x += y;
    }
    int ex = x - v;  // exclusive prefix
    lcur[t] = ex;
    int n = b * 64 + t;
    if (n < N_NODES) {
      row_start[n] = b * CAP + ex;
      counts[n] = v;
      dis[n] = rsqrtf((float)v + 1.0f);
    }
  }
  __syncthreads();
  for (int i = t; i < cnt; i += 256) {
    int r = eraw[b * CAP + i];
    int pos = atomicAdd(&lcur[(r >> 20) & 63], 1);
    esrt[b * CAP + pos] = r;  // writes stay within this bucket's 8 KB window
  }
}

// ---------------- GEMM: xwb = bf16(x @ W1) ----------------
// Block 256 -> 32 rows x 128 cols, thread = 4 rows x 4 cols. Row = 64 uints.
__global__ __launch_bounds__(256) void gemm_xw(const float* __restrict__ x,
                                               const float* __restrict__ Wg,
                                               unsigned int* __restrict__ xwb) {
  __shared__ float Wl[32 * 128];
  __shared__ float Xlt[32 * 36];
  int t = threadIdx.x;
  int r0 = blockIdx.x * 32;        // 100000 = 32 * 3125 exactly
  int tx = t & 31, ty = t >> 5;
  float acc[4][4] = {};

  for (int kb = 0; kb < 4; ++kb) {
    __syncthreads();
#pragma unroll
    for (int i = 0; i < 4; ++i) {
      int f = (i * 256 + t) * 4;
      *(float4*)&Wl[f] = *(const float4*)&Wg[kb * 32 * 128 + f];
    }
    {
      int row = t >> 3, kk = (t & 7) * 4;
      float4 v = *(const float4*)&x[(r0 + row) * 128 + kb * 32 + kk];
      Xlt[(kk + 0) * 36 + row] = v.x;
      Xlt[(kk + 1) * 36 + row] = v.y;
      Xlt[(kk + 2) * 36 + row] = v.z;
      Xlt[(kk + 3) * 36 + row] = v.w;
    }
    __syncthreads();
#pragma unroll
    for (int k = 0; k < 32; ++k) {
      float4 wv = *(float4*)&Wl[k * 128 + tx * 4];
      float4 xv = *(float4*)&Xlt[k * 36 + ty * 4];
      float xr[4] = {xv.x, xv.y, xv.z, xv.w};
#pragma unroll
      for (int i = 0; i < 4; ++i) {
        acc[i][0] += xr[i] * wv.x;
        acc[i][1] += xr[i] * wv.y;
        acc[i][2] += xr[i] * wv.z;
        acc[i][3] += xr[i] * wv.w;
      }
    }
  }
#pragma unroll
  for (int i = 0; i < 4; ++i) {
    unsigned lo = ((unsigned)f2bf(acc[i][1]) << 16) | f2bf(acc[i][0]);
    unsigned hi = ((unsigned)f2bf(acc[i][3]) << 16) | f2bf(acc[i][2]);
    int row = r0 + ty * 4 + i;
    *(uint2*)&xwb[row * 64 + tx * 2] = make_uint2(lo, hi);
  }
}

// ---------------- Layer-1 aggregation (wave per dst) fused with (h @ W2) ----------
// 2 edges per load instruction: half = lane>>5 picks the edge, sublane owns 4 ch
// (uint2 = 8B). 4-deep unroll -> 8 edges/wave in flight. norm = dis[s]*dis[wid]
// computed on the fly (dis is L2-resident).
__global__ __launch_bounds__(256) void agg1_kernel(const unsigned int* __restrict__ xwb,
                                                   const float* __restrict__ b1,
                                                   const float* __restrict__ W2,
                                                   const float* __restrict__ dis,
                                                   const int* __restrict__ row_start,
                                                   const int* __restrict__ counts,
                                                   const int* __restrict__ esrt,
                                                   float* __restrict__ hw) {
  int wid = blockIdx.x * 4 + (threadIdx.x >> 6);
  if (wid >= N_NODES) return;
  int lane = threadIdx.x & 63;
  int half = lane >> 5;
  int sub = lane & 31;
  int c = sub * 4;                        // this lane's 4 channels
  int start = row_start[wid];
  int cnt = counts[wid];
  float disw = dis[wid];
  const uint2* xw2 = (const uint2*)xwb;   // row = node*32 uint2 (256B/row)

  float a0 = 0.f, a1 = 0.f, a2 = 0.f, a3 = 0.f;

  for (int i = 0; i < cnt; i += 8) {
#pragma unroll
    for (int k = 0; k < 4; ++k) {
      int ei = i + 2 * k + half;
      bool valid = ei < cnt;
      int r = esrt[valid ? (start + ei) : start];
      int s = r & 0xFFFFF;
      float n = valid ? dis[s] * disw : 0.0f;
      uint2 g = xw2[s * 32 + sub];
      a0 += bf_lo(g.x) * n;
      a1 += bf_hi(g.x) * n;
      a2 += bf_lo(g.y) * n;
      a3 += bf_hi(g.y) * n;
    }
  }
  // combine the two edge-halves: lanes l and l+32 hold partial sums of same channels
  a0 += __shfl_xor(a0, 32);
  a1 += __shfl_xor(a1, 32);
  a2 += __shfl_xor(a2, 32);
  a3 += __shfl_xor(a3, 32);

  float dsq = disw * disw;
  uint2 gs = xw2[wid * 32 + sub];
  float4 bv = *(const float4*)&b1[c];
  a0 += bf_lo(gs.x) * dsq + bv.x;
  a1 += bf_hi(gs.x) * dsq + bv.y;
  a2 += bf_lo(gs.y) * dsq + bv.z;
  a3 += bf_hi(gs.y) * dsq + bv.w;
  a0 = fmaxf(a0, 0.f); a1 = fmaxf(a1, 0.f);
  a2 = fmaxf(a2, 0.f); a3 = fmaxf(a3, 0.f);

  // project 4 channels -> 2 outputs: W2 rows c..c+3 are 8 consecutive floats
  float4 w01 = *(const float4*)&W2[c * 2];      // rows c, c+1
  float4 w23 = *(const float4*)&W2[c * 2 + 4];  // rows c+2, c+3
  float p0 = a0 * w01.x + a1 * w01.z + a2 * w23.x + a3 * w23.z;
  float p1 = a0 * w01.y + a1 * w01.w + a2 * w23.y + a3 * w23.w;
#pragma unroll
  for (int off = 16; off >= 1; off >>= 1) {
    p0 += __shfl_xor(p0, off);
    p1 += __shfl_xor(p1, off);
  }
  if (lane == 0) *(float2*)&hw[wid * 2] = make_float2(p0, p1);
}

// ---------------- Layer-2 aggregation (2 channels, wave per dst) ----------------
__global__ __launch_bounds__(256) void agg2_kernel(const float* __restrict__ hw,
                                                   const float* __restrict__ b2,
                                                   const float* __restrict__ dis,
                                                   const int* __restrict__ row_start,
                                                   const int* __restrict__ counts,
                                                   const int* __restrict__ esrt,
                                                   float* __restrict__ out) {
  int wid = blockIdx.x * 4 + (threadIdx.x >> 6);
  if (wid >= N_NODES) return;
  int lane = threadIdx.x & 63;
  int start = row_start[wid];
  int cnt = counts[wid];
  float disw = dis[wid];
  float a0 = 0.f, a1 = 0.f;
  for (int i = lane; i < cnt; i += 64) {
    int r = esrt[start + i];
    int s = r & 0xFFFFF;
    float n = dis[s] * disw;
    float2 v = *(const float2*)&hw[s * 2];
    a0 += v.x * n;
    a1 += v.y * n;
  }
#pragma unroll
  for (int off = 32; off >= 1; off >>= 1) {
    a0 += __shfl_xor(a0, off);
    a1 += __shfl_xor(a1, off);
  }
  if (lane == 0) {
    float dsq = disw * disw;
    float2 vd = *(const float2*)&hw[wid * 2];
    out[wid * 2 + 0] = a0 + vd.x * dsq + b2[0];
    out[wid * 2 + 1] = a1 + vd.y * dsq + b2[1];
  }
}

// ---------------- launch ----------------

extern "C" void kernel_launch(void* const* d_in, const int* in_sizes, int n_in,
                              void* d_out, int out_size, void* d_ws, size_t ws_size,
                              hipStream_t stream) {
  const float* x  = (const float*)d_in[0];
  const int*   ei = (const int*)d_in[1];
  const float* W1 = (const float*)d_in[2];
  const float* b1 = (const float*)d_in[3];
  const float* W2 = (const float*)d_in[4];
  const float* b2 = (const float*)d_in[5];
  float* out = (float*)d_out;

  const int* src = ei;            // edge_index[0]
  const int* dst = ei + N_EDGES;  // edge_index[1]

  char* ws = (char*)d_ws;
  size_t off = 0;
  auto walloc = [&](size_t bytes) -> void* {
    void* p = ws + off;
    off += (bytes + 255) & ~(size_t)255;
    return p;
  };
  unsigned int* xwb = (unsigned int*)walloc((size_t)N_NODES * 128 * 2);  // 25.6 MB bf16
  int*   cursor     = (int*)walloc((size_t)NB * 4);
  int*   eraw       = (int*)walloc((size_t)NB * CAP * 4);                // 12.8 MB
  int*   esrt       = (int*)walloc((size_t)NB * CAP * 4);                // 12.8 MB
  int*   row_start  = (int*)walloc((size_t)N_NODES * 4);
  int*   counts     = (int*)walloc((size_t)N_NODES * 4);
  float* dis        = (float*)walloc((size_t)N_NODES * 4);
  float* hw         = (float*)walloc((size_t)N_NODES * 2 * 4);

  if (off > ws_size) return;  // workspace too small: fail visibly, don't corrupt memory

  hipMemsetAsync(cursor, 0, (size_t)NB * 4, stream);

  scatter_bucket<<<(N_EDGES + 255) / 256, 256, 0, stream>>>(src, dst, cursor, eraw);
  bucket_sort<<<NB, 256, 0, stream>>>(cursor, eraw, esrt, row_start, counts, dis);
  gemm_xw<<<N_NODES / 32, 256, 0, stream>>>(x, W1, xwb);
  agg1_kernel<<<(N_NODES + 3) / 4, 256, 0, stream>>>(xwb, b1, W2, dis, row_start, counts,
                                                     esrt, hw);
  agg2_kernel<<<(N_NODES + 3) / 4, 256, 0, stream>>>(hw, b2, dis, row_start, counts,
                                                     esrt, out);
}

// Round 8
// 377.894 us; speedup vs baseline: 4.4674x; 1.4200x over previous
//
#include <hip/hip_runtime.h>

#define N_NODES 100000
#define N_EDGES 1600000
#define NB 1563            // ceil(100000/64) buckets of 64 dst nodes
#define NSUB 8             // per-XCD sub-buckets (blockIdx & 7 heuristic)
#define SCAP 256           // capacity per (bucket, sub): mean 128, +11 sigma
#define CAP 2048           // per-bucket total = NSUB * SCAP
// IN=128, HID=128, OUT=2

__device__ __forceinline__ int clamp_idx(int v) {
  return v < 0 ? 0 : (v >= N_NODES ? N_NODES - 1 : v);
}

__device__ __forceinline__ unsigned short f2bf(float f) {
  unsigned u = __float_as_uint(f);
  unsigned r = ((u >> 16) & 1u) + 0x7fffu;  // round-to-nearest-even
  return (unsigned short)((u + r) >> 16);
}
__device__ __forceinline__ float bf_lo(unsigned u) { return __uint_as_float(u << 16); }
__device__ __forceinline__ float bf_hi(unsigned u) { return __uint_as_float(u & 0xffff0000u); }

// ---------------- bucketed scatter, XCD-partitioned ----------------
// Record = {src | ldst<<20} (4B). Cell (b,sub) is written only by blocks with
// blockIdx&7==sub -> active lines + cursors stay in ONE XCD's L2.
__global__ __launch_bounds__(256) void scatter_bucket(const int* __restrict__ src,
                                                      const int* __restrict__ dst,
                                                      int* __restrict__ cursor,
                                                      int* __restrict__ eraw) {
  int e = blockIdx.x * 256 + threadIdx.x;
  int sub = blockIdx.x & (NSUB - 1);
  if (e < N_EDGES) {
    int s = clamp_idx(src[e]), d = clamp_idx(dst[e]);
    int b = d >> 6;
    int cell = b * NSUB + sub;
    int pos = atomicAdd(&cursor[cell], 1);
    if (pos < SCAP) eraw[cell * SCAP + pos] = s | ((d & 63) << 20);
  }
}

// ---------------- per-bucket LDS counting sort -> node-sorted CSR ----------------
// Block per bucket; merges the 8 sub-segments. Emits counts, row_start, dis.
__global__ __launch_bounds__(256) void bucket_sort(const int* __restrict__ cursor,
                                                   const int* __restrict__ eraw,
                                                   int* __restrict__ esrt,
                                                   int* __restrict__ row_start,
                                                   int* __restrict__ counts,
                                                   float* __restrict__ dis) {
  __shared__ int hist[64];
  __shared__ int lcur[64];
  __shared__ int scnt[NSUB];
  int b = blockIdx.x;
  int t = threadIdx.x;
  if (t < NSUB) {
    int c = cursor[b * NSUB + t];
    scnt[t] = c > SCAP ? SCAP : c;
  }
  if (t < 64) hist[t] = 0;
  __syncthreads();
  // histogram over the 8 sub-segments (8*256 slots / 256 threads = 8 steps)
  for (int idx = t; idx < NSUB * SCAP; idx += 256) {
    int sub = idx >> 8;          // SCAP == 256
    int i = idx & (SCAP - 1);
    if (i < scnt[sub]) {
      atomicAdd(&hist[(eraw[(b * NSUB + sub) * SCAP + i] >> 20) & 63], 1);
    }
  }
  __syncthreads();
  if (t < 64) {  // wave 0: 64-wide exclusive scan via shfl
    int v = hist[t];
    int x = v;
#pragma unroll
    for (int dlt = 1; dlt < 64; dlt <<= 1) {
      int y = __shfl_up(x, dlt);
      if (t >= dlt) x += y;
    }
    int ex = x - v;  // exclusive prefix
    lcur[t] = ex;
    int n = b * 64 + t;
    if (n < N_NODES) {
      row_start[n] = b * CAP + ex;
      counts[n] = v;
      dis[n] = rsqrtf((float)v + 1.0f);
    }
  }
  __syncthreads();
  for (int idx = t; idx < NSUB * SCAP; idx += 256) {
    int sub = idx >> 8;
    int i = idx & (SCAP - 1);
    if (i < scnt[sub]) {
      int r = eraw[(b * NSUB + sub) * SCAP + i];
      int pos = atomicAdd(&lcur[(r >> 20) & 63], 1);
      esrt[b * CAP + pos] = r;  // stays within this bucket's 8 KB window
    }
  }
}

// ---------------- GEMM: xwb = bf16(x @ W1) ----------------
// Block 256 -> 32 rows x 128 cols, thread = 4 rows x 4 cols. Row = 64 uints.
__global__ __launch_bounds__(256) void gemm_xw(const float* __restrict__ x,
                                               const float* __restrict__ Wg,
                                               unsigned int* __restrict__ xwb) {
  __shared__ float Wl[32 * 128];
  __shared__ float Xlt[32 * 36];
  int t = threadIdx.x;
  int r0 = blockIdx.x * 32;        // 100000 = 32 * 3125 exactly
  int tx = t & 31, ty = t >> 5;
  float acc[4][4] = {};

  for (int kb = 0; kb < 4; ++kb) {
    __syncthreads();
#pragma unroll
    for (int i = 0; i < 4; ++i) {
      int f = (i * 256 + t) * 4;
      *(float4*)&Wl[f] = *(const float4*)&Wg[kb * 32 * 128 + f];
    }
    {
      int row = t >> 3, kk = (t & 7) * 4;
      float4 v = *(const float4*)&x[(r0 + row) * 128 + kb * 32 + kk];
      Xlt[(kk + 0) * 36 + row] = v.x;
      Xlt[(kk + 1) * 36 + row] = v.y;
      Xlt[(kk + 2) * 36 + row] = v.z;
      Xlt[(kk + 3) * 36 + row] = v.w;
    }
    __syncthreads();
#pragma unroll
    for (int k = 0; k < 32; ++k) {
      float4 wv = *(float4*)&Wl[k * 128 + tx * 4];
      float4 xv = *(float4*)&Xlt[k * 36 + ty * 4];
      float xr[4] = {xv.x, xv.y, xv.z, xv.w};
#pragma unroll
      for (int i = 0; i < 4; ++i) {
        acc[i][0] += xr[i] * wv.x;
        acc[i][1] += xr[i] * wv.y;
        acc[i][2] += xr[i] * wv.z;
        acc[i][3] += xr[i] * wv.w;
      }
    }
  }
#pragma unroll
  for (int i = 0; i < 4; ++i) {
    unsigned lo = ((unsigned)f2bf(acc[i][1]) << 16) | f2bf(acc[i][0]);
    unsigned hi = ((unsigned)f2bf(acc[i][3]) << 16) | f2bf(acc[i][2]);
    int row = r0 + ty * 4 + i;
    *(uint2*)&xwb[row * 64 + tx * 2] = make_uint2(lo, hi);
  }
}

// ---------------- Layer-1 aggregation (wave per dst) fused with (h @ W2) ----------
// 2 edges per load instruction: half = lane>>5 picks the edge, sublane owns 4 ch
// (uint2 = 8B). 4-deep unroll -> 8 edges/wave in flight. norm = dis[s]*dis[wid].
__global__ __launch_bounds__(256) void agg1_kernel(const unsigned int* __restrict__ xwb,
                                                   const float* __restrict__ b1,
                                                   const float* __restrict__ W2,
                                                   const float* __restrict__ dis,
                                                   const int* __restrict__ row_start,
                                                   const int* __restrict__ counts,
                                                   const int* __restrict__ esrt,
                                                   float* __restrict__ hw) {
  int wid = blockIdx.x * 4 + (threadIdx.x >> 6);
  if (wid >= N_NODES) return;
  int lane = threadIdx.x & 63;
  int half = lane >> 5;
  int sub = lane & 31;
  int c = sub * 4;                        // this lane's 4 channels
  int start = row_start[wid];
  int cnt = counts[wid];
  float disw = dis[wid];
  const uint2* xw2 = (const uint2*)xwb;   // row = node*32 uint2 (256B/row)

  float a0 = 0.f, a1 = 0.f, a2 = 0.f, a3 = 0.f;

  for (int i = 0; i < cnt; i += 8) {
#pragma unroll
    for (int k = 0; k < 4; ++k) {
      int ei = i + 2 * k + half;
      bool valid = ei < cnt;
      int r = esrt[valid ? (start + ei) : start];
      int s = r & 0xFFFFF;
      float n = valid ? dis[s] * disw : 0.0f;
      uint2 g = xw2[s * 32 + sub];
      a0 += bf_lo(g.x) * n;
      a1 += bf_hi(g.x) * n;
      a2 += bf_lo(g.y) * n;
      a3 += bf_hi(g.y) * n;
    }
  }
  a0 += __shfl_xor(a0, 32);
  a1 += __shfl_xor(a1, 32);
  a2 += __shfl_xor(a2, 32);
  a3 += __shfl_xor(a3, 32);

  float dsq = disw * disw;
  uint2 gs = xw2[wid * 32 + sub];
  float4 bv = *(const float4*)&b1[c];
  a0 += bf_lo(gs.x) * dsq + bv.x;
  a1 += bf_hi(gs.x) * dsq + bv.y;
  a2 += bf_lo(gs.y) * dsq + bv.z;
  a3 += bf_hi(gs.y) * dsq + bv.w;
  a0 = fmaxf(a0, 0.f); a1 = fmaxf(a1, 0.f);
  a2 = fmaxf(a2, 0.f); a3 = fmaxf(a3, 0.f);

  float4 w01 = *(const float4*)&W2[c * 2];      // W2 rows c, c+1
  float4 w23 = *(const float4*)&W2[c * 2 + 4];  // W2 rows c+2, c+3
  float p0 = a0 * w01.x + a1 * w01.z + a2 * w23.x + a3 * w23.z;
  float p1 = a0 * w01.y + a1 * w01.w + a2 * w23.y + a3 * w23.w;
#pragma unroll
  for (int off = 16; off >= 1; off >>= 1) {
    p0 += __shfl_xor(p0, off);
    p1 += __shfl_xor(p1, off);
  }
  if (lane == 0) *(float2*)&hw[wid * 2] = make_float2(p0, p1);
}

// ---------------- Layer-2 aggregation (2 channels, wave per dst) ----------------
__global__ __launch_bounds__(256) void agg2_kernel(const float* __restrict__ hw,
                                                   const float* __restrict__ b2,
                                                   const float* __restrict__ dis,
                                                   const int* __restrict__ row_start,
                                                   const int* __restrict__ counts,
                                                   const int* __restrict__ esrt,
                                                   float* __restrict__ out) {
  int wid = blockIdx.x * 4 + (threadIdx.x >> 6);
  if (wid >= N_NODES) return;
  int lane = threadIdx.x & 63;
  int start = row_start[wid];
  int cnt = counts[wid];
  float disw = dis[wid];
  float a0 = 0.f, a1 = 0.f;
  for (int i = lane; i < cnt; i += 64) {
    int r = esrt[start + i];
    int s = r & 0xFFFFF;
    float n = dis[s] * disw;
    float2 v = *(const float2*)&hw[s * 2];
    a0 += v.x * n;
    a1 += v.y * n;
  }
#pragma unroll
  for (int off = 32; off >= 1; off >>= 1) {
    a0 += __shfl_xor(a0, off);
    a1 += __shfl_xor(a1, off);
  }
  if (lane == 0) {
    float dsq = disw * disw;
    float2 vd = *(const float2*)&hw[wid * 2];
    out[wid * 2 + 0] = a0 + vd.x * dsq + b2[0];
    out[wid * 2 + 1] = a1 + vd.y * dsq + b2[1];
  }
}

// ---------------- launch ----------------

extern "C" void kernel_launch(void* const* d_in, const int* in_sizes, int n_in,
                              void* d_out, int out_size, void* d_ws, size_t ws_size,
                              hipStream_t stream) {
  const float* x  = (const float*)d_in[0];
  const int*   ei = (const int*)d_in[1];
  const float* W1 = (const float*)d_in[2];
  const float* b1 = (const float*)d_in[3];
  const float* W2 = (const float*)d_in[4];
  const float* b2 = (const float*)d_in[5];
  float* out = (float*)d_out;

  const int* src = ei;            // edge_index[0]
  const int* dst = ei + N_EDGES;  // edge_index[1]

  char* ws = (char*)d_ws;
  size_t off = 0;
  auto walloc = [&](size_t bytes) -> void* {
    void* p = ws + off;
    off += (bytes + 255) & ~(size_t)255;
    return p;
  };
  unsigned int* xwb = (unsigned int*)walloc((size_t)N_NODES * 128 * 2);   // 25.6 MB bf16
  int*   cursor     = (int*)walloc((size_t)NB * NSUB * 4);                // 50 KB
  int*   eraw       = (int*)walloc((size_t)NB * NSUB * SCAP * 4);         // 12.8 MB
  int*   esrt       = (int*)walloc((size_t)NB * CAP * 4);                 // 12.8 MB
  int*   row_start  = (int*)walloc((size_t)N_NODES * 4);
  int*   counts     = (int*)walloc((size_t)N_NODES * 4);
  float* dis        = (float*)walloc((size_t)N_NODES * 4);
  float* hw         = (float*)walloc((size_t)N_NODES * 2 * 4);

  if (off > ws_size) return;  // workspace too small: fail visibly, don't corrupt memory

  hipMemsetAsync(cursor, 0, (size_t)NB * NSUB * 4, stream);

  scatter_bucket<<<(N_EDGES + 255) / 256, 256, 0, stream>>>(src, dst, cursor, eraw);
  bucket_sort<<<NB, 256, 0, stream>>>(cursor, eraw, esrt, row_start, counts, dis);
  gemm_xw<<<N_NODES / 32, 256, 0, stream>>>(x, W1, xwb);
  agg1_kernel<<<(N_NODES + 3) / 4, 256, 0, stream>>>(xwb, b1, W2, dis, row_start, counts,
                                                     esrt, hw);
  agg2_kernel<<<(N_NODES + 3) / 4, 256, 0, stream>>>(hw, b2, dis, row_start, counts,
                                                     esrt, out);
}

// Round 9
// 355.178 us; speedup vs baseline: 4.7532x; 1.0640x over previous
//
#include <hip/hip_runtime.h>

#define N_NODES 100000
#define N_EDGES 1600000
#define NB 1563            // ceil(100000/64) buckets of 64 dst nodes
#define NSUB 8             // per-XCD sub-buckets (blockIdx & 7 heuristic)
#define SCAP 256           // capacity per (bucket, sub): mean 128, +11 sigma
#define CAP 2048           // per-bucket total = NSUB * SCAP
// IN=128, HID=128, OUT=2

__device__ __forceinline__ int clamp_idx(int v) {
  return v < 0 ? 0 : (v >= N_NODES ? N_NODES - 1 : v);
}

__device__ __forceinline__ unsigned short f2bf(float f) {
  unsigned u = __float_as_uint(f);
  unsigned r = ((u >> 16) & 1u) + 0x7fffu;  // round-to-nearest-even
  return (unsigned short)((u + r) >> 16);
}
__device__ __forceinline__ float bf_lo(unsigned u) { return __uint_as_float(u << 16); }
__device__ __forceinline__ float bf_hi(unsigned u) { return __uint_as_float(u & 0xffff0000u); }

// ---------------- bucketed scatter, XCD-partitioned ----------------
// Record = {src | ldst<<20} (4B). Cell (b,sub) is written only by blocks with
// blockIdx&7==sub -> active lines + cursors stay in ONE XCD's L2.
__global__ __launch_bounds__(256) void scatter_bucket(const int* __restrict__ src,
                                                      const int* __restrict__ dst,
                                                      int* __restrict__ cursor,
                                                      int* __restrict__ eraw) {
  int e = blockIdx.x * 256 + threadIdx.x;
  int sub = blockIdx.x & (NSUB - 1);
  if (e < N_EDGES) {
    int s = clamp_idx(src[e]), d = clamp_idx(dst[e]);
    int b = d >> 6;
    int cell = b * NSUB + sub;
    int pos = atomicAdd(&cursor[cell], 1);
    if (pos < SCAP) eraw[cell * SCAP + pos] = s | ((d & 63) << 20);
  }
}

// ---------------- per-bucket LDS counting sort -> node-sorted CSR ----------------
// Block per bucket; merges the 8 sub-segments. Emits counts, row_start, dis.
__global__ __launch_bounds__(256) void bucket_sort(const int* __restrict__ cursor,
                                                   const int* __restrict__ eraw,
                                                   int* __restrict__ esrt,
                                                   int* __restrict__ row_start,
                                                   int* __restrict__ counts,
                                                   float* __restrict__ dis) {
  __shared__ int hist[64];
  __shared__ int lcur[64];
  __shared__ int scnt[NSUB];
  int b = blockIdx.x;
  int t = threadIdx.x;
  if (t < NSUB) {
    int c = cursor[b * NSUB + t];
    scnt[t] = c > SCAP ? SCAP : c;
  }
  if (t < 64) hist[t] = 0;
  __syncthreads();
  // histogram over the 8 sub-segments (8*256 slots / 256 threads = 8 steps)
  for (int idx = t; idx < NSUB * SCAP; idx += 256) {
    int sub = idx >> 8;          // SCAP == 256
    int i = idx & (SCAP - 1);
    if (i < scnt[sub]) {
      atomicAdd(&hist[(eraw[(b * NSUB + sub) * SCAP + i] >> 20) & 63], 1);
    }
  }
  __syncthreads();
  if (t < 64) {  // wave 0: 64-wide exclusive scan via shfl
    int v = hist[t];
    int x = v;
#pragma unroll
    for (int dlt = 1; dlt < 64; dlt <<= 1) {
      int y = __shfl_up(x, dlt);
      if (t >= dlt) x += y;
    }
    int ex = x - v;  // exclusive prefix
    lcur[t] = ex;
    int n = b * 64 + t;
    if (n < N_NODES) {
      row_start[n] = b * CAP + ex;
      counts[n] = v;
      dis[n] = rsqrtf((float)v + 1.0f);
    }
  }
  __syncthreads();
  for (int idx = t; idx < NSUB * SCAP; idx += 256) {
    int sub = idx >> 8;
    int i = idx & (SCAP - 1);
    if (i < scnt[sub]) {
      int r = eraw[(b * NSUB + sub) * SCAP + i];
      int pos = atomicAdd(&lcur[(r >> 20) & 63], 1);
      esrt[b * CAP + pos] = r;  // stays within this bucket's 8 KB window
    }
  }
}

// ---------------- GEMM: xwb = bf16(x @ W1) ----------------
// Block 256 -> 32 rows x 128 cols, thread = 4 rows x 4 cols. Row = 64 uints.
__global__ __launch_bounds__(256) void gemm_xw(const float* __restrict__ x,
                                               const float* __restrict__ Wg,
                                               unsigned int* __restrict__ xwb) {
  __shared__ float Wl[32 * 128];
  __shared__ float Xlt[32 * 36];
  int t = threadIdx.x;
  int r0 = blockIdx.x * 32;        // 100000 = 32 * 3125 exactly
  int tx = t & 31, ty = t >> 5;
  float acc[4][4] = {};

  for (int kb = 0; kb < 4; ++kb) {
    __syncthreads();
#pragma unroll
    for (int i = 0; i < 4; ++i) {
      int f = (i * 256 + t) * 4;
      *(float4*)&Wl[f] = *(const float4*)&Wg[kb * 32 * 128 + f];
    }
    {
      int row = t >> 3, kk = (t & 7) * 4;
      float4 v = *(const float4*)&x[(r0 + row) * 128 + kb * 32 + kk];
      Xlt[(kk + 0) * 36 + row] = v.x;
      Xlt[(kk + 1) * 36 + row] = v.y;
      Xlt[(kk + 2) * 36 + row] = v.z;
      Xlt[(kk + 3) * 36 + row] = v.w;
    }
    __syncthreads();
#pragma unroll
    for (int k = 0; k < 32; ++k) {
      float4 wv = *(float4*)&Wl[k * 128 + tx * 4];
      float4 xv = *(float4*)&Xlt[k * 36 + ty * 4];
      float xr[4] = {xv.x, xv.y, xv.z, xv.w};
#pragma unroll
      for (int i = 0; i < 4; ++i) {
        acc[i][0] += xr[i] * wv.x;
        acc[i][1] += xr[i] * wv.y;
        acc[i][2] += xr[i] * wv.z;
        acc[i][3] += xr[i] * wv.w;
      }
    }
  }
#pragma unroll
  for (int i = 0; i < 4; ++i) {
    unsigned lo = ((unsigned)f2bf(acc[i][1]) << 16) | f2bf(acc[i][0]);
    unsigned hi = ((unsigned)f2bf(acc[i][3]) << 16) | f2bf(acc[i][2]);
    int row = r0 + ty * 4 + i;
    *(uint2*)&xwb[row * 64 + tx * 2] = make_uint2(lo, hi);
  }
}

// ---------------- Layer-1 aggregation (wave per dst) fused with (h @ W2) ----------
// 4 edges per load step: quarter q = lane>>4 picks the edge, sub = lane&15 owns
// 8 channels (uint4 = 16B). 4-deep unroll -> 16 edges/wave in flight (avg degree
// is 16 -> typical node completes in ONE iteration). norm = dis[s]*dis[wid].
__global__ __launch_bounds__(256) void agg1_kernel(const unsigned int* __restrict__ xwb,
                                                   const float* __restrict__ b1,
                                                   const float* __restrict__ W2,
                                                   const float* __restrict__ dis,
                                                   const int* __restrict__ row_start,
                                                   const int* __restrict__ counts,
                                                   const int* __restrict__ esrt,
                                                   float* __restrict__ hw) {
  int wid = blockIdx.x * 4 + (threadIdx.x >> 6);
  if (wid >= N_NODES) return;
  int lane = threadIdx.x & 63;
  int q = lane >> 4;                      // edge quarter 0..3
  int sub = lane & 15;                    // channel group: 8 ch = 16B
  int c = sub * 8;
  int start = row_start[wid];
  int cnt = counts[wid];
  float disw = dis[wid];
  const uint4* xw4 = (const uint4*)xwb;   // row = node*16 uint4 (256B/row)

  float a0 = 0.f, a1 = 0.f, a2 = 0.f, a3 = 0.f;
  float a4 = 0.f, a5 = 0.f, a6 = 0.f, a7 = 0.f;

  for (int i = 0; i < cnt; i += 16) {
#pragma unroll
    for (int k = 0; k < 4; ++k) {
      int ei = i + 4 * k + q;
      bool valid = ei < cnt;
      int r = esrt[valid ? (start + ei) : start];
      int s = r & 0xFFFFF;
      float n = valid ? dis[s] * disw : 0.0f;
      uint4 g = xw4[s * 16 + sub];
      a0 += bf_lo(g.x) * n; a1 += bf_hi(g.x) * n;
      a2 += bf_lo(g.y) * n; a3 += bf_hi(g.y) * n;
      a4 += bf_lo(g.z) * n; a5 += bf_hi(g.z) * n;
      a6 += bf_lo(g.w) * n; a7 += bf_hi(g.w) * n;
    }
  }
  // combine the four edge-quarters (lanes sub, sub+16, sub+32, sub+48 share channels)
  a0 += __shfl_xor(a0, 16); a1 += __shfl_xor(a1, 16);
  a2 += __shfl_xor(a2, 16); a3 += __shfl_xor(a3, 16);
  a4 += __shfl_xor(a4, 16); a5 += __shfl_xor(a5, 16);
  a6 += __shfl_xor(a6, 16); a7 += __shfl_xor(a7, 16);
  a0 += __shfl_xor(a0, 32); a1 += __shfl_xor(a1, 32);
  a2 += __shfl_xor(a2, 32); a3 += __shfl_xor(a3, 32);
  a4 += __shfl_xor(a4, 32); a5 += __shfl_xor(a5, 32);
  a6 += __shfl_xor(a6, 32); a7 += __shfl_xor(a7, 32);

  float dsq = disw * disw;
  uint4 gs = xw4[wid * 16 + sub];
  float4 bv0 = *(const float4*)&b1[c];
  float4 bv1 = *(const float4*)&b1[c + 4];
  a0 += bf_lo(gs.x) * dsq + bv0.x;
  a1 += bf_hi(gs.x) * dsq + bv0.y;
  a2 += bf_lo(gs.y) * dsq + bv0.z;
  a3 += bf_hi(gs.y) * dsq + bv0.w;
  a4 += bf_lo(gs.z) * dsq + bv1.x;
  a5 += bf_hi(gs.z) * dsq + bv1.y;
  a6 += bf_lo(gs.w) * dsq + bv1.z;
  a7 += bf_hi(gs.w) * dsq + bv1.w;
  a0 = fmaxf(a0, 0.f); a1 = fmaxf(a1, 0.f);
  a2 = fmaxf(a2, 0.f); a3 = fmaxf(a3, 0.f);
  a4 = fmaxf(a4, 0.f); a5 = fmaxf(a5, 0.f);
  a6 = fmaxf(a6, 0.f); a7 = fmaxf(a7, 0.f);

  // project 8 channels -> 2 outputs: W2 rows c..c+7 = 16 consecutive floats
  float4 wA = *(const float4*)&W2[c * 2];       // rows c,   c+1
  float4 wB = *(const float4*)&W2[c * 2 + 4];   // rows c+2, c+3
  float4 wC = *(const float4*)&W2[c * 2 + 8];   // rows c+4, c+5
  float4 wD = *(const float4*)&W2[c * 2 + 12];  // rows c+6, c+7
  float p0 = a0 * wA.x + a1 * wA.z + a2 * wB.x + a3 * wB.z +
             a4 * wC.x + a5 * wC.z + a6 * wD.x + a7 * wD.z;
  float p1 = a0 * wA.y + a1 * wA.w + a2 * wB.y + a3 * wB.w +
             a4 * wC.y + a5 * wC.w + a6 * wD.y + a7 * wD.w;
#pragma unroll
  for (int off = 8; off >= 1; off >>= 1) {
    p0 += __shfl_xor(p0, off);
    p1 += __shfl_xor(p1, off);
  }
  if (lane == 0) *(float2*)&hw[wid * 2] = make_float2(p0, p1);
}

// ---------------- Layer-2 aggregation (2 channels, wave per dst) ----------------
__global__ __launch_bounds__(256) void agg2_kernel(const float* __restrict__ hw,
                                                   const float* __restrict__ b2,
                                                   const float* __restrict__ dis,
                                                   const int* __restrict__ row_start,
                                                   const int* __restrict__ counts,
                                                   const int* __restrict__ esrt,
                                                   float* __restrict__ out) {
  int wid = blockIdx.x * 4 + (threadIdx.x >> 6);
  if (wid >= N_NODES) return;
  int lane = threadIdx.x & 63;
  int start = row_start[wid];
  int cnt = counts[wid];
  float disw = dis[wid];
  float a0 = 0.f, a1 = 0.f;
  for (int i = lane; i < cnt; i += 64) {
    int r = esrt[start + i];
    int s = r & 0xFFFFF;
    float n = dis[s] * disw;
    float2 v = *(const float2*)&hw[s * 2];
    a0 += v.x * n;
    a1 += v.y * n;
  }
#pragma unroll
  for (int off = 32; off >= 1; off >>= 1) {
    a0 += __shfl_xor(a0, off);
    a1 += __shfl_xor(a1, off);
  }
  if (lane == 0) {
    float dsq = disw * disw;
    float2 vd = *(const float2*)&hw[wid * 2];
    out[wid * 2 + 0] = a0 + vd.x * dsq + b2[0];
    out[wid * 2 + 1] = a1 + vd.y * dsq + b2[1];
  }
}

// ---------------- launch ----------------

extern "C" void kernel_launch(void* const* d_in, const int* in_sizes, int n_in,
                              void* d_out, int out_size, void* d_ws, size_t ws_size,
                              hipStream_t stream) {
  const float* x  = (const float*)d_in[0];
  const int*   ei = (const int*)d_in[1];
  const float* W1 = (const float*)d_in[2];
  const float* b1 = (const float*)d_in[3];
  const float* W2 = (const float*)d_in[4];
  const float* b2 = (const float*)d_in[5];
  float* out = (float*)d_out;

  const int* src = ei;            // edge_index[0]
  const int* dst = ei + N_EDGES;  // edge_index[1]

  char* ws = (char*)d_ws;
  size_t off = 0;
  auto walloc = [&](size_t bytes) -> void* {
    void* p = ws + off;
    off += (bytes + 255) & ~(size_t)255;
    return p;
  };
  unsigned int* xwb = (unsigned int*)walloc((size_t)N_NODES * 128 * 2);   // 25.6 MB bf16
  int*   cursor     = (int*)walloc((size_t)NB * NSUB * 4);                // 50 KB
  int*   eraw       = (int*)walloc((size_t)NB * NSUB * SCAP * 4);         // 12.8 MB
  int*   esrt       = (int*)walloc((size_t)NB * CAP * 4);                 // 12.8 MB
  int*   row_start  = (int*)walloc((size_t)N_NODES * 4);
  int*   counts     = (int*)walloc((size_t)N_NODES * 4);
  float* dis        = (float*)walloc((size_t)N_NODES * 4);
  float* hw         = (float*)walloc((size_t)N_NODES * 2 * 4);

  if (off > ws_size) return;  // workspace too small: fail visibly, don't corrupt memory

  hipMemsetAsync(cursor, 0, (size_t)NB * NSUB * 4, stream);

  scatter_bucket<<<(N_EDGES + 255) / 256, 256, 0, stream>>>(src, dst, cursor, eraw);
  bucket_sort<<<NB, 256, 0, stream>>>(cursor, eraw, esrt, row_start, counts, dis);
  gemm_xw<<<N_NODES / 32, 256, 0, stream>>>(x, W1, xwb);
  agg1_kernel<<<(N_NODES + 3) / 4, 256, 0, stream>>>(xwb, b1, W2, dis, row_start, counts,
                                                     esrt, hw);
  agg2_kernel<<<(N_NODES + 3) / 4, 256, 0, stream>>>(hw, b2, dis, row_start, counts,
                                                     esrt, out);
}

// Round 10
// 326.091 us; speedup vs baseline: 5.1771x; 1.0892x over previous
//
#include <hip/hip_runtime.h>

#define N_NODES 100000
#define N_EDGES 1600000
#define NB 1563            // ceil(100000/64) buckets of 64 dst nodes
#define NSUB 8             // per-XCD sub-buckets (blockIdx & 7 heuristic)
#define SCAP 256           // capacity per (bucket, sub): mean 128, +11 sigma
#define CAP 2048           // per-bucket total = NSUB * SCAP
// IN=128, HID=128, OUT=2

__device__ __forceinline__ int clamp_idx(int v) {
  return v < 0 ? 0 : (v >= N_NODES ? N_NODES - 1 : v);
}

__device__ __forceinline__ unsigned short f2bf(float f) {
  unsigned u = __float_as_uint(f);
  unsigned r = ((u >> 16) & 1u) + 0x7fffu;  // round-to-nearest-even
  return (unsigned short)((u + r) >> 16);
}
__device__ __forceinline__ float bf_lo(unsigned u) { return __uint_as_float(u << 16); }
__device__ __forceinline__ float bf_hi(unsigned u) { return __uint_as_float(u & 0xffff0000u); }

// ---------------- bucketed scatter, XCD-partitioned (4B records) ----------------
__global__ __launch_bounds__(256) void scatter_bucket(const int* __restrict__ src,
                                                      const int* __restrict__ dst,
                                                      int* __restrict__ cursor,
                                                      int* __restrict__ eraw) {
  int e = blockIdx.x * 256 + threadIdx.x;
  int sub = blockIdx.x & (NSUB - 1);
  if (e < N_EDGES) {
    int s = clamp_idx(src[e]), d = clamp_idx(dst[e]);
    int b = d >> 6;
    int cell = b * NSUB + sub;
    int pos = atomicAdd(&cursor[cell], 1);
    if (pos < SCAP) eraw[cell * SCAP + pos] = s | ((d & 63) << 20);
  }
}

// ---------------- pass A: histogram + scan -> counts, row_start, dis ----------------
__global__ __launch_bounds__(256) void sort_hist(const int* __restrict__ cursor,
                                                 const int* __restrict__ eraw,
                                                 int* __restrict__ row_start,
                                                 int* __restrict__ counts,
                                                 float* __restrict__ dis) {
  __shared__ int hist[64];
  __shared__ int scnt[NSUB];
  int b = blockIdx.x;
  int t = threadIdx.x;
  if (t < NSUB) {
    int c = cursor[b * NSUB + t];
    scnt[t] = c > SCAP ? SCAP : c;
  }
  if (t < 64) hist[t] = 0;
  __syncthreads();
  for (int idx = t; idx < NSUB * SCAP; idx += 256) {
    int sub = idx >> 8;          // SCAP == 256
    int i = idx & (SCAP - 1);
    if (i < scnt[sub]) {
      atomicAdd(&hist[(eraw[(b * NSUB + sub) * SCAP + i] >> 20) & 63], 1);
    }
  }
  __syncthreads();
  if (t < 64) {  // wave 0: 64-wide exclusive scan via shfl
    int v = hist[t];
    int x = v;
#pragma unroll
    for (int dlt = 1; dlt < 64; dlt <<= 1) {
      int y = __shfl_up(x, dlt);
      if (t >= dlt) x += y;
    }
    int ex = x - v;  // exclusive prefix
    int n = b * 64 + t;
    if (n < N_NODES) {
      row_start[n] = b * CAP + ex;
      counts[n] = v;
      dis[n] = rsqrtf((float)v + 1.0f);
    }
  }
}

// ---------------- pass B: place records with baked norm -> int2{src, norm} ----------
__global__ __launch_bounds__(256) void sort_place(const int* __restrict__ cursor,
                                                  const int* __restrict__ eraw,
                                                  const int* __restrict__ counts,
                                                  const float* __restrict__ dis,
                                                  int2* __restrict__ erec) {
  __shared__ int lcur[64];
  __shared__ float ldis[64];
  __shared__ int scnt[NSUB];
  int b = blockIdx.x;
  int t = threadIdx.x;
  if (t < NSUB) {
    int c = cursor[b * NSUB + t];
    scnt[t] = c > SCAP ? SCAP : c;
  }
  if (t < 64) {  // rebuild exclusive scan from counts; stage bucket dis
    int n = b * 64 + t;
    int v = (n < N_NODES) ? counts[n] : 0;
    ldis[t] = (n < N_NODES) ? dis[n] : 0.f;
    int x = v;
#pragma unroll
    for (int dlt = 1; dlt < 64; dlt <<= 1) {
      int y = __shfl_up(x, dlt);
      if (t >= dlt) x += y;
    }
    lcur[t] = x - v;
  }
  __syncthreads();
  for (int idx = t; idx < NSUB * SCAP; idx += 256) {
    int sub = idx >> 8;
    int i = idx & (SCAP - 1);
    if (i < scnt[sub]) {
      int r = eraw[(b * NSUB + sub) * SCAP + i];
      int s = r & 0xFFFFF;
      int ld = (r >> 20) & 63;
      int pos = atomicAdd(&lcur[ld], 1);
      float norm = dis[s] * ldis[ld];
      erec[b * CAP + pos] = make_int2(s, __float_as_int(norm));
    }
  }
}

// ---------------- GEMM: xwb = bf16(x @ W1) ----------------
// Block 256 -> 32 rows x 128 cols, thread = 4 rows x 4 cols. Row = 64 uints.
__global__ __launch_bounds__(256) void gemm_xw(const float* __restrict__ x,
                                               const float* __restrict__ Wg,
                                               unsigned int* __restrict__ xwb) {
  __shared__ float Wl[32 * 128];
  __shared__ float Xlt[32 * 36];
  int t = threadIdx.x;
  int r0 = blockIdx.x * 32;        // 100000 = 32 * 3125 exactly
  int tx = t & 31, ty = t >> 5;
  float acc[4][4] = {};

  for (int kb = 0; kb < 4; ++kb) {
    __syncthreads();
#pragma unroll
    for (int i = 0; i < 4; ++i) {
      int f = (i * 256 + t) * 4;
      *(float4*)&Wl[f] = *(const float4*)&Wg[kb * 32 * 128 + f];
    }
    {
      int row = t >> 3, kk = (t & 7) * 4;
      float4 v = *(const float4*)&x[(r0 + row) * 128 + kb * 32 + kk];
      Xlt[(kk + 0) * 36 + row] = v.x;
      Xlt[(kk + 1) * 36 + row] = v.y;
      Xlt[(kk + 2) * 36 + row] = v.z;
      Xlt[(kk + 3) * 36 + row] = v.w;
    }
    __syncthreads();
#pragma unroll
    for (int k = 0; k < 32; ++k) {
      float4 wv = *(float4*)&Wl[k * 128 + tx * 4];
      float4 xv = *(float4*)&Xlt[k * 36 + ty * 4];
      float xr[4] = {xv.x, xv.y, xv.z, xv.w};
#pragma unroll
      for (int i = 0; i < 4; ++i) {
        acc[i][0] += xr[i] * wv.x;
        acc[i][1] += xr[i] * wv.y;
        acc[i][2] += xr[i] * wv.z;
        acc[i][3] += xr[i] * wv.w;
      }
    }
  }
#pragma unroll
  for (int i = 0; i < 4; ++i) {
    unsigned lo = ((unsigned)f2bf(acc[i][1]) << 16) | f2bf(acc[i][0]);
    unsigned hi = ((unsigned)f2bf(acc[i][3]) << 16) | f2bf(acc[i][2]);
    int row = r0 + ty * 4 + i;
    *(uint2*)&xwb[row * 64 + tx * 2] = make_uint2(lo, hi);
  }
}

// ---------------- Layer-1 aggregation (wave per dst) fused with (h @ W2) ----------
// 4 edges per load step: quarter q = lane>>4 picks the edge, sub = lane&15 owns
// 8 channels (uint4 = 16B). Records carry baked norm -> single-level load chain.
__global__ __launch_bounds__(256) void agg1_kernel(const unsigned int* __restrict__ xwb,
                                                   const float* __restrict__ b1,
                                                   const float* __restrict__ W2,
                                                   const float* __restrict__ dis,
                                                   const int* __restrict__ row_start,
                                                   const int* __restrict__ counts,
                                                   const int2* __restrict__ erec,
                                                   float* __restrict__ hw) {
  int wid = blockIdx.x * 4 + (threadIdx.x >> 6);
  if (wid >= N_NODES) return;
  int lane = threadIdx.x & 63;
  int q = lane >> 4;                      // edge quarter 0..3
  int sub = lane & 15;                    // channel group: 8 ch = 16B
  int c = sub * 8;
  int start = row_start[wid];
  int cnt = counts[wid];
  const uint4* xw4 = (const uint4*)xwb;   // row = node*16 uint4 (256B/row)

  float a0 = 0.f, a1 = 0.f, a2 = 0.f, a3 = 0.f;
  float a4 = 0.f, a5 = 0.f, a6 = 0.f, a7 = 0.f;

  for (int i = 0; i < cnt; i += 16) {
#pragma unroll
    for (int k = 0; k < 4; ++k) {
      int ei = i + 4 * k + q;
      bool valid = ei < cnt;
      int2 rec = erec[valid ? (start + ei) : start];
      int s = rec.x;
      float n = valid ? __int_as_float(rec.y) : 0.0f;
      uint4 g = xw4[s * 16 + sub];
      a0 += bf_lo(g.x) * n; a1 += bf_hi(g.x) * n;
      a2 += bf_lo(g.y) * n; a3 += bf_hi(g.y) * n;
      a4 += bf_lo(g.z) * n; a5 += bf_hi(g.z) * n;
      a6 += bf_lo(g.w) * n; a7 += bf_hi(g.w) * n;
    }
  }
  // combine the four edge-quarters (lanes sub, sub+16, sub+32, sub+48 share channels)
  a0 += __shfl_xor(a0, 16); a1 += __shfl_xor(a1, 16);
  a2 += __shfl_xor(a2, 16); a3 += __shfl_xor(a3, 16);
  a4 += __shfl_xor(a4, 16); a5 += __shfl_xor(a5, 16);
  a6 += __shfl_xor(a6, 16); a7 += __shfl_xor(a7, 16);
  a0 += __shfl_xor(a0, 32); a1 += __shfl_xor(a1, 32);
  a2 += __shfl_xor(a2, 32); a3 += __shfl_xor(a3, 32);
  a4 += __shfl_xor(a4, 32); a5 += __shfl_xor(a5, 32);
  a6 += __shfl_xor(a6, 32); a7 += __shfl_xor(a7, 32);

  float disw = dis[wid];
  float dsq = disw * disw;
  uint4 gs = xw4[wid * 16 + sub];
  float4 bv0 = *(const float4*)&b1[c];
  float4 bv1 = *(const float4*)&b1[c + 4];
  a0 += bf_lo(gs.x) * dsq + bv0.x;
  a1 += bf_hi(gs.x) * dsq + bv0.y;
  a2 += bf_lo(gs.y) * dsq + bv0.z;
  a3 += bf_hi(gs.y) * dsq + bv0.w;
  a4 += bf_lo(gs.z) * dsq + bv1.x;
  a5 += bf_hi(gs.z) * dsq + bv1.y;
  a6 += bf_lo(gs.w) * dsq + bv1.z;
  a7 += bf_hi(gs.w) * dsq + bv1.w;
  a0 = fmaxf(a0, 0.f); a1 = fmaxf(a1, 0.f);
  a2 = fmaxf(a2, 0.f); a3 = fmaxf(a3, 0.f);
  a4 = fmaxf(a4, 0.f); a5 = fmaxf(a5, 0.f);
  a6 = fmaxf(a6, 0.f); a7 = fmaxf(a7, 0.f);

  // project 8 channels -> 2 outputs: W2 rows c..c+7 = 16 consecutive floats
  float4 wA = *(const float4*)&W2[c * 2];
  float4 wB = *(const float4*)&W2[c * 2 + 4];
  float4 wC = *(const float4*)&W2[c * 2 + 8];
  float4 wD = *(const float4*)&W2[c * 2 + 12];
  float p0 = a0 * wA.x + a1 * wA.z + a2 * wB.x + a3 * wB.z +
             a4 * wC.x + a5 * wC.z + a6 * wD.x + a7 * wD.z;
  float p1 = a0 * wA.y + a1 * wA.w + a2 * wB.y + a3 * wB.w +
             a4 * wC.y + a5 * wC.w + a6 * wD.y + a7 * wD.w;
#pragma unroll
  for (int off = 8; off >= 1; off >>= 1) {
    p0 += __shfl_xor(p0, off);
    p1 += __shfl_xor(p1, off);
  }
  if (lane == 0) *(float2*)&hw[wid * 2] = make_float2(p0, p1);
}

// ---------------- Layer-2 aggregation: 4 nodes per wave (16 lanes each) ----------
__global__ __launch_bounds__(256) void agg2_kernel(const float* __restrict__ hw,
                                                   const float* __restrict__ b2,
                                                   const float* __restrict__ dis,
                                                   const int* __restrict__ row_start,
                                                   const int* __restrict__ counts,
                                                   const int2* __restrict__ erec,
                                                   float* __restrict__ out) {
  int tid = threadIdx.x;
  int wid = blockIdx.x * 16 + (tid >> 4);  // node per 16-lane group
  if (wid >= N_NODES) return;
  int sub = tid & 15;
  int start = row_start[wid];
  int cnt = counts[wid];
  float a0 = 0.f, a1 = 0.f;
  for (int i = sub; i < cnt; i += 16) {
    int2 rec = erec[start + i];
    float n = __int_as_float(rec.y);
    float2 v = *(const float2*)&hw[rec.x * 2];
    a0 += v.x * n;
    a1 += v.y * n;
  }
#pragma unroll
  for (int off = 8; off >= 1; off >>= 1) {
    a0 += __shfl_xor(a0, off);
    a1 += __shfl_xor(a1, off);
  }
  if (sub == 0) {
    float disw = dis[wid];
    float dsq = disw * disw;
    float2 vd = *(const float2*)&hw[wid * 2];
    out[wid * 2 + 0] = a0 + vd.x * dsq + b2[0];
    out[wid * 2 + 1] = a1 + vd.y * dsq + b2[1];
  }
}

// ---------------- launch ----------------

extern "C" void kernel_launch(void* const* d_in, const int* in_sizes, int n_in,
                              void* d_out, int out_size, void* d_ws, size_t ws_size,
                              hipStream_t stream) {
  const float* x  = (const float*)d_in[0];
  const int*   ei = (const int*)d_in[1];
  const float* W1 = (const float*)d_in[2];
  const float* b1 = (const float*)d_in[3];
  const float* W2 = (const float*)d_in[4];
  const float* b2 = (const float*)d_in[5];
  float* out = (float*)d_out;

  const int* src = ei;            // edge_index[0]
  const int* dst = ei + N_EDGES;  // edge_index[1]

  char* ws = (char*)d_ws;
  size_t off = 0;
  auto walloc = [&](size_t bytes) -> void* {
    void* p = ws + off;
    off += (bytes + 255) & ~(size_t)255;
    return p;
  };
  unsigned int* xwb = (unsigned int*)walloc((size_t)N_NODES * 128 * 2);   // 25.6 MB bf16
  int*   cursor     = (int*)walloc((size_t)NB * NSUB * 4);                // 50 KB
  int*   eraw       = (int*)walloc((size_t)NB * NSUB * SCAP * 4);         // 12.8 MB
  int2*  erec       = (int2*)walloc((size_t)NB * CAP * 8);                // 25.6 MB
  int*   row_start  = (int*)walloc((size_t)N_NODES * 4);
  int*   counts     = (int*)walloc((size_t)N_NODES * 4);
  float* dis        = (float*)walloc((size_t)N_NODES * 4);
  float* hw         = (float*)walloc((size_t)N_NODES * 2 * 4);

  if (off > ws_size) return;  // workspace too small: fail visibly, don't corrupt memory

  hipMemsetAsync(cursor, 0, (size_t)NB * NSUB * 4, stream);

  scatter_bucket<<<(N_EDGES + 255) / 256, 256, 0, stream>>>(src, dst, cursor, eraw);
  sort_hist<<<NB, 256, 0, stream>>>(cursor, eraw, row_start, counts, dis);
  sort_place<<<NB, 256, 0, stream>>>(cursor, eraw, counts, dis, erec);
  gemm_xw<<<N_NODES / 32, 256, 0, stream>>>(x, W1, xwb);
  agg1_kernel<<<(N_NODES + 3) / 4, 256, 0, stream>>>(xwb, b1, W2, dis, row_start, counts,
                                                     erec, hw);
  agg2_kernel<<<(N_NODES + 15) / 16, 256, 0, stream>>>(hw, b2, dis, row_start, counts,
                                                       erec, out);
}

// Round 11
// 322.233 us; speedup vs baseline: 5.2391x; 1.0120x over previous
//
#include <hip/hip_runtime.h>

#define N_NODES 100000
#define N_EDGES 1600000
#define NB 1563            // ceil(100000/64) buckets of 64 dst nodes
#define NSUB 8             // per-XCD sub-buckets (blockIdx & 7 heuristic)
#define SCAP 256           // capacity per (bucket, sub): mean 128, +11 sigma
#define CAP 2048           // per-bucket total = NSUB * SCAP
// IN=128, HID=128, OUT=2

__device__ __forceinline__ int clamp_idx(int v) {
  return v < 0 ? 0 : (v >= N_NODES ? N_NODES - 1 : v);
}

__device__ __forceinline__ unsigned short f2bf(float f) {
  unsigned u = __float_as_uint(f);
  unsigned r = ((u >> 16) & 1u) + 0x7fffu;  // round-to-nearest-even
  return (unsigned short)((u + r) >> 16);
}
__device__ __forceinline__ float bf_lo(unsigned u) { return __uint_as_float(u << 16); }
__device__ __forceinline__ float bf_hi(unsigned u) { return __uint_as_float(u & 0xffff0000u); }

// ---------------- bucketed scatter, XCD-partitioned, SUB-MAJOR layout ----------------
// cell = sub*NB + b  ->  each sub's active frontier is a contiguous 1.6 MB region:
// L2 set index spreads over all 2048 sets instead of 32 (stride-8KB aliasing).
__global__ __launch_bounds__(256) void scatter_bucket(const int* __restrict__ src,
                                                      const int* __restrict__ dst,
                                                      int* __restrict__ cursor,
                                                      int* __restrict__ eraw) {
  int e = blockIdx.x * 256 + threadIdx.x;
  int sub = blockIdx.x & (NSUB - 1);
  if (e < N_EDGES) {
    int s = clamp_idx(src[e]), d = clamp_idx(dst[e]);
    int b = d >> 6;
    int cell = sub * NB + b;
    int pos = atomicAdd(&cursor[cell], 1);
    if (pos < SCAP) eraw[cell * SCAP + pos] = s | ((d & 63) << 20);
  }
}

// ---------------- pass A: histogram + scan -> counts, row_start, dis ----------------
__global__ __launch_bounds__(256) void sort_hist(const int* __restrict__ cursor,
                                                 const int* __restrict__ eraw,
                                                 int* __restrict__ row_start,
                                                 int* __restrict__ counts,
                                                 float* __restrict__ dis) {
  __shared__ int hist[64];
  __shared__ int scnt[NSUB];
  int b = blockIdx.x;
  int t = threadIdx.x;
  if (t < NSUB) {
    int c = cursor[t * NB + b];
    scnt[t] = c > SCAP ? SCAP : c;
  }
  if (t < 64) hist[t] = 0;
  __syncthreads();
  for (int idx = t; idx < NSUB * SCAP; idx += 256) {
    int sub = idx >> 8;          // SCAP == 256
    int i = idx & (SCAP - 1);
    if (i < scnt[sub]) {
      atomicAdd(&hist[(eraw[(sub * NB + b) * SCAP + i] >> 20) & 63], 1);
    }
  }
  __syncthreads();
  if (t < 64) {  // wave 0: 64-wide exclusive scan via shfl
    int v = hist[t];
    int x = v;
#pragma unroll
    for (int dlt = 1; dlt < 64; dlt <<= 1) {
      int y = __shfl_up(x, dlt);
      if (t >= dlt) x += y;
    }
    int ex = x - v;  // exclusive prefix
    int n = b * 64 + t;
    if (n < N_NODES) {
      row_start[n] = b * CAP + ex;
      counts[n] = v;
      dis[n] = rsqrtf((float)v + 1.0f);
    }
  }
}

// ---------------- pass B: place records with baked norm -> int2{src, norm} ----------
__global__ __launch_bounds__(256) void sort_place(const int* __restrict__ cursor,
                                                  const int* __restrict__ eraw,
                                                  const int* __restrict__ counts,
                                                  const float* __restrict__ dis,
                                                  int2* __restrict__ erec) {
  __shared__ int lcur[64];
  __shared__ float ldis[64];
  __shared__ int scnt[NSUB];
  int b = blockIdx.x;
  int t = threadIdx.x;
  if (t < NSUB) {
    int c = cursor[t * NB + b];
    scnt[t] = c > SCAP ? SCAP : c;
  }
  if (t < 64) {  // rebuild exclusive scan from counts; stage bucket dis
    int n = b * 64 + t;
    int v = (n < N_NODES) ? counts[n] : 0;
    ldis[t] = (n < N_NODES) ? dis[n] : 0.f;
    int x = v;
#pragma unroll
    for (int dlt = 1; dlt < 64; dlt <<= 1) {
      int y = __shfl_up(x, dlt);
      if (t >= dlt) x += y;
    }
    lcur[t] = x - v;
  }
  __syncthreads();
  for (int idx = t; idx < NSUB * SCAP; idx += 256) {
    int sub = idx >> 8;
    int i = idx & (SCAP - 1);
    if (i < scnt[sub]) {
      int r = eraw[(sub * NB + b) * SCAP + i];
      int s = r & 0xFFFFF;
      int ld = (r >> 20) & 63;
      int pos = atomicAdd(&lcur[ld], 1);
      float norm = dis[s] * ldis[ld];
      erec[b * CAP + pos] = make_int2(s, __float_as_int(norm));
    }
  }
}

// ---------------- GEMM: xwb = bf16(x @ W1) ----------------
// Block 256 -> 32 rows x 128 cols, thread = 4 rows x 4 cols. Row = 64 uints.
__global__ __launch_bounds__(256) void gemm_xw(const float* __restrict__ x,
                                               const float* __restrict__ Wg,
                                               unsigned int* __restrict__ xwb) {
  __shared__ float Wl[32 * 128];
  __shared__ float Xlt[32 * 36];
  int t = threadIdx.x;
  int r0 = blockIdx.x * 32;        // 100000 = 32 * 3125 exactly
  int tx = t & 31, ty = t >> 5;
  float acc[4][4] = {};

  for (int kb = 0; kb < 4; ++kb) {
    __syncthreads();
#pragma unroll
    for (int i = 0; i < 4; ++i) {
      int f = (i * 256 + t) * 4;
      *(float4*)&Wl[f] = *(const float4*)&Wg[kb * 32 * 128 + f];
    }
    {
      int row = t >> 3, kk = (t & 7) * 4;
      float4 v = *(const float4*)&x[(r0 + row) * 128 + kb * 32 + kk];
      Xlt[(kk + 0) * 36 + row] = v.x;
      Xlt[(kk + 1) * 36 + row] = v.y;
      Xlt[(kk + 2) * 36 + row] = v.z;
      Xlt[(kk + 3) * 36 + row] = v.w;
    }
    __syncthreads();
#pragma unroll
    for (int k = 0; k < 32; ++k) {
      float4 wv = *(float4*)&Wl[k * 128 + tx * 4];
      float4 xv = *(float4*)&Xlt[k * 36 + ty * 4];
      float xr[4] = {xv.x, xv.y, xv.z, xv.w};
#pragma unroll
      for (int i = 0; i < 4; ++i) {
        acc[i][0] += xr[i] * wv.x;
        acc[i][1] += xr[i] * wv.y;
        acc[i][2] += xr[i] * wv.z;
        acc[i][3] += xr[i] * wv.w;
      }
    }
  }
#pragma unroll
  for (int i = 0; i < 4; ++i) {
    unsigned lo = ((unsigned)f2bf(acc[i][1]) << 16) | f2bf(acc[i][0]);
    unsigned hi = ((unsigned)f2bf(acc[i][3]) << 16) | f2bf(acc[i][2]);
    int row = r0 + ty * 4 + i;
    *(uint2*)&xwb[row * 64 + tx * 2] = make_uint2(lo, hi);
  }
}

// ---------------- Layer-1 aggregation (wave per dst) fused with (h @ W2) ----------
// 4 edges per load step: quarter q = lane>>4 picks the edge, sub = lane&15 owns
// 8 channels (uint4 = 16B). Records carry baked norm -> single-level load chain.
__global__ __launch_bounds__(256) void agg1_kernel(const unsigned int* __restrict__ xwb,
                                                   const float* __restrict__ b1,
                                                   const float* __restrict__ W2,
                                                   const float* __restrict__ dis,
                                                   const int* __restrict__ row_start,
                                                   const int* __restrict__ counts,
                                                   const int2* __restrict__ erec,
                                                   float* __restrict__ hw) {
  int wid = blockIdx.x * 4 + (threadIdx.x >> 6);
  if (wid >= N_NODES) return;
  int lane = threadIdx.x & 63;
  int q = lane >> 4;                      // edge quarter 0..3
  int sub = lane & 15;                    // channel group: 8 ch = 16B
  int c = sub * 8;
  int start = row_start[wid];
  int cnt = counts[wid];
  const uint4* xw4 = (const uint4*)xwb;   // row = node*16 uint4 (256B/row)

  float a0 = 0.f, a1 = 0.f, a2 = 0.f, a3 = 0.f;
  float a4 = 0.f, a5 = 0.f, a6 = 0.f, a7 = 0.f;

  for (int i = 0; i < cnt; i += 16) {
#pragma unroll
    for (int k = 0; k < 4; ++k) {
      int ei = i + 4 * k + q;
      bool valid = ei < cnt;
      int2 rec = erec[valid ? (start + ei) : start];
      int s = rec.x;
      float n = valid ? __int_as_float(rec.y) : 0.0f;
      uint4 g = xw4[s * 16 + sub];
      a0 += bf_lo(g.x) * n; a1 += bf_hi(g.x) * n;
      a2 += bf_lo(g.y) * n; a3 += bf_hi(g.y) * n;
      a4 += bf_lo(g.z) * n; a5 += bf_hi(g.z) * n;
      a6 += bf_lo(g.w) * n; a7 += bf_hi(g.w) * n;
    }
  }
  // combine the four edge-quarters (lanes sub, sub+16, sub+32, sub+48 share channels)
  a0 += __shfl_xor(a0, 16); a1 += __shfl_xor(a1, 16);
  a2 += __shfl_xor(a2, 16); a3 += __shfl_xor(a3, 16);
  a4 += __shfl_xor(a4, 16); a5 += __shfl_xor(a5, 16);
  a6 += __shfl_xor(a6, 16); a7 += __shfl_xor(a7, 16);
  a0 += __shfl_xor(a0, 32); a1 += __shfl_xor(a1, 32);
  a2 += __shfl_xor(a2, 32); a3 += __shfl_xor(a3, 32);
  a4 += __shfl_xor(a4, 32); a5 += __shfl_xor(a5, 32);
  a6 += __shfl_xor(a6, 32); a7 += __shfl_xor(a7, 32);

  float disw = dis[wid];
  float dsq = disw * disw;
  uint4 gs = xw4[wid * 16 + sub];
  float4 bv0 = *(const float4*)&b1[c];
  float4 bv1 = *(const float4*)&b1[c + 4];
  a0 += bf_lo(gs.x) * dsq + bv0.x;
  a1 += bf_hi(gs.x) * dsq + bv0.y;
  a2 += bf_lo(gs.y) * dsq + bv0.z;
  a3 += bf_hi(gs.y) * dsq + bv0.w;
  a4 += bf_lo(gs.z) * dsq + bv1.x;
  a5 += bf_hi(gs.z) * dsq + bv1.y;
  a6 += bf_lo(gs.w) * dsq + bv1.z;
  a7 += bf_hi(gs.w) * dsq + bv1.w;
  a0 = fmaxf(a0, 0.f); a1 = fmaxf(a1, 0.f);
  a2 = fmaxf(a2, 0.f); a3 = fmaxf(a3, 0.f);
  a4 = fmaxf(a4, 0.f); a5 = fmaxf(a5, 0.f);
  a6 = fmaxf(a6, 0.f); a7 = fmaxf(a7, 0.f);

  // project 8 channels -> 2 outputs: W2 rows c..c+7 = 16 consecutive floats
  float4 wA = *(const float4*)&W2[c * 2];
  float4 wB = *(const float4*)&W2[c * 2 + 4];
  float4 wC = *(const float4*)&W2[c * 2 + 8];
  float4 wD = *(const float4*)&W2[c * 2 + 12];
  float p0 = a0 * wA.x + a1 * wA.z + a2 * wB.x + a3 * wB.z +
             a4 * wC.x + a5 * wC.z + a6 * wD.x + a7 * wD.z;
  float p1 = a0 * wA.y + a1 * wA.w + a2 * wB.y + a3 * wB.w +
             a4 * wC.y + a5 * wC.w + a6 * wD.y + a7 * wD.w;
#pragma unroll
  for (int off = 8; off >= 1; off >>= 1) {
    p0 += __shfl_xor(p0, off);
    p1 += __shfl_xor(p1, off);
  }
  if (lane == 0) *(float2*)&hw[wid * 2] = make_float2(p0, p1);
}

// ---------------- Layer-2 aggregation: 4 nodes per wave (16 lanes each) ----------
__global__ __launch_bounds__(256) void agg2_kernel(const float* __restrict__ hw,
                                                   const float* __restrict__ b2,
                                                   const float* __restrict__ dis,
                                                   const int* __restrict__ row_start,
                                                   const int* __restrict__ counts,
                                                   const int2* __restrict__ erec,
                                                   float* __restrict__ out) {
  int tid = threadIdx.x;
  int wid = blockIdx.x * 16 + (tid >> 4);  // node per 16-lane group
  if (wid >= N_NODES) return;
  int sub = tid & 15;
  int start = row_start[wid];
  int cnt = counts[wid];
  float a0 = 0.f, a1 = 0.f;
  for (int i = sub; i < cnt; i += 16) {
    int2 rec = erec[start + i];
    float n = __int_as_float(rec.y);
    float2 v = *(const float2*)&hw[rec.x * 2];
    a0 += v.x * n;
    a1 += v.y * n;
  }
#pragma unroll
  for (int off = 8; off >= 1; off >>= 1) {
    a0 += __shfl_xor(a0, off);
    a1 += __shfl_xor(a1, off);
  }
  if (sub == 0) {
    float disw = dis[wid];
    float dsq = disw * disw;
    float2 vd = *(const float2*)&hw[wid * 2];
    out[wid * 2 + 0] = a0 + vd.x * dsq + b2[0];
    out[wid * 2 + 1] = a1 + vd.y * dsq + b2[1];
  }
}

// ---------------- launch ----------------

extern "C" void kernel_launch(void* const* d_in, const int* in_sizes, int n_in,
                              void* d_out, int out_size, void* d_ws, size_t ws_size,
                              hipStream_t stream) {
  const float* x  = (const float*)d_in[0];
  const int*   ei = (const int*)d_in[1];
  const float* W1 = (const float*)d_in[2];
  const float* b1 = (const float*)d_in[3];
  const float* W2 = (const float*)d_in[4];
  const float* b2 = (const float*)d_in[5];
  float* out = (float*)d_out;

  const int* src = ei;            // edge_index[0]
  const int* dst = ei + N_EDGES;  // edge_index[1]

  char* ws = (char*)d_ws;
  size_t off = 0;
  auto walloc = [&](size_t bytes) -> void* {
    void* p = ws + off;
    off += (bytes + 255) & ~(size_t)255;
    return p;
  };
  unsigned int* xwb = (unsigned int*)walloc((size_t)N_NODES * 128 * 2);   // 25.6 MB bf16
  int*   cursor     = (int*)walloc((size_t)NB * NSUB * 4);                // 50 KB
  int*   eraw       = (int*)walloc((size_t)NB * NSUB * SCAP * 4);         // 12.8 MB
  int2*  erec       = (int2*)walloc((size_t)NB * CAP * 8);                // 25.6 MB
  int*   row_start  = (int*)walloc((size_t)N_NODES * 4);
  int*   counts     = (int*)walloc((size_t)N_NODES * 4);
  float* dis        = (float*)walloc((size_t)N_NODES * 4);
  float* hw         = (float*)walloc((size_t)N_NODES * 2 * 4);

  if (off > ws_size) return;  // workspace too small: fail visibly, don't corrupt memory

  hipMemsetAsync(cursor, 0, (size_t)NB * NSUB * 4, stream);

  scatter_bucket<<<(N_EDGES + 255) / 256, 256, 0, stream>>>(src, dst, cursor, eraw);
  sort_hist<<<NB, 256, 0, stream>>>(cursor, eraw, row_start, counts, dis);
  sort_place<<<NB, 256, 0, stream>>>(cursor, eraw, counts, dis, erec);
  gemm_xw<<<N_NODES / 32, 256, 0, stream>>>(x, W1, xwb);
  agg1_kernel<<<(N_NODES + 3) / 4, 256, 0, stream>>>(xwb, b1, W2, dis, row_start, counts,
                                                     erec, hw);
  agg2_kernel<<<(N_NODES + 15) / 16, 256, 0, stream>>>(hw, b2, dis, row_start, counts,
                                                       erec, out);
}

// Round 12
// 311.551 us; speedup vs baseline: 5.4188x; 1.0343x over previous
//
#include <hip/hip_runtime.h>

#define N_NODES 100000
#define N_EDGES 1600000
#define NB 1563            // ceil(100000/64) buckets of 64 dst nodes
#define NSUB 8             // per-XCD sub-buckets (real XCC_ID)
#define SCAP 256           // capacity per (bucket, sub): mean 128, +11 sigma
#define CAP 2048           // per-bucket total = NSUB * SCAP
#define CSTRIDE 32         // cursor padding: 1 cursor per 128B line
// IN=128, HID=128, OUT=2

__device__ __forceinline__ int clamp_idx(int v) {
  return v < 0 ? 0 : (v >= N_NODES ? N_NODES - 1 : v);
}

__device__ __forceinline__ unsigned short f2bf(float f) {
  unsigned u = __float_as_uint(f);
  unsigned r = ((u >> 16) & 1u) + 0x7fffu;  // round-to-nearest-even
  return (unsigned short)((u + r) >> 16);
}
__device__ __forceinline__ float bf_lo(unsigned u) { return __uint_as_float(u << 16); }
__device__ __forceinline__ float bf_hi(unsigned u) { return __uint_as_float(u & 0xffff0000u); }

// ---------------- bucketed scatter: real-XCD partition + padded cursors ----------------
// sub = hardware XCC_ID -> each (bucket,sub) cell + its cursor line are touched by
// exactly ONE XCD's L2 (no dispatch-mapping assumption). Cursor per 128B line.
__global__ __launch_bounds__(256) void scatter_bucket(const int* __restrict__ src,
                                                      const int* __restrict__ dst,
                                                      int* __restrict__ cursor,
                                                      int* __restrict__ eraw) {
  unsigned xcc;
  asm volatile("s_getreg_b32 %0, hwreg(HW_REG_XCC_ID)" : "=s"(xcc));
  int sub = (int)(xcc & (NSUB - 1));
  int e = blockIdx.x * 256 + threadIdx.x;
  if (e < N_EDGES) {
    int s = clamp_idx(src[e]), d = clamp_idx(dst[e]);
    int b = d >> 6;
    int cell = sub * NB + b;
    int pos = atomicAdd(&cursor[cell * CSTRIDE], 1);
    if (pos < SCAP) eraw[cell * SCAP + pos] = s | ((d & 63) << 20);
  }
}

// ---------------- pass A: histogram + scan -> counts, row_start, dis ----------------
__global__ __launch_bounds__(256) void sort_hist(const int* __restrict__ cursor,
                                                 const int* __restrict__ eraw,
                                                 int* __restrict__ row_start,
                                                 int* __restrict__ counts,
                                                 float* __restrict__ dis) {
  __shared__ int hist[64];
  __shared__ int scnt[NSUB];
  int b = blockIdx.x;
  int t = threadIdx.x;
  if (t < NSUB) {
    int c = cursor[(t * NB + b) * CSTRIDE];
    scnt[t] = c > SCAP ? SCAP : c;
  }
  if (t < 64) hist[t] = 0;
  __syncthreads();
  for (int idx = t; idx < NSUB * SCAP; idx += 256) {
    int sub = idx >> 8;          // SCAP == 256
    int i = idx & (SCAP - 1);
    if (i < scnt[sub]) {
      atomicAdd(&hist[(eraw[(sub * NB + b) * SCAP + i] >> 20) & 63], 1);
    }
  }
  __syncthreads();
  if (t < 64) {  // wave 0: 64-wide exclusive scan via shfl
    int v = hist[t];
    int x = v;
#pragma unroll
    for (int dlt = 1; dlt < 64; dlt <<= 1) {
      int y = __shfl_up(x, dlt);
      if (t >= dlt) x += y;
    }
    int ex = x - v;  // exclusive prefix
    int n = b * 64 + t;
    if (n < N_NODES) {
      row_start[n] = b * CAP + ex;
      counts[n] = v;
      dis[n] = rsqrtf((float)v + 1.0f);
    }
  }
}

// ---------------- pass B: place records with baked norm -> int2{src, norm} ----------
__global__ __launch_bounds__(256) void sort_place(const int* __restrict__ cursor,
                                                  const int* __restrict__ eraw,
                                                  const int* __restrict__ counts,
                                                  const float* __restrict__ dis,
                                                  int2* __restrict__ erec) {
  __shared__ int lcur[64];
  __shared__ float ldis[64];
  __shared__ int scnt[NSUB];
  int b = blockIdx.x;
  int t = threadIdx.x;
  if (t < NSUB) {
    int c = cursor[(t * NB + b) * CSTRIDE];
    scnt[t] = c > SCAP ? SCAP : c;
  }
  if (t < 64) {  // rebuild exclusive scan from counts; stage bucket dis
    int n = b * 64 + t;
    int v = (n < N_NODES) ? counts[n] : 0;
    ldis[t] = (n < N_NODES) ? dis[n] : 0.f;
    int x = v;
#pragma unroll
    for (int dlt = 1; dlt < 64; dlt <<= 1) {
      int y = __shfl_up(x, dlt);
      if (t >= dlt) x += y;
    }
    lcur[t] = x - v;
  }
  __syncthreads();
  for (int idx = t; idx < NSUB * SCAP; idx += 256) {
    int sub = idx >> 8;
    int i = idx & (SCAP - 1);
    if (i < scnt[sub]) {
      int r = eraw[(sub * NB + b) * SCAP + i];
      int s = r & 0xFFFFF;
      int ld = (r >> 20) & 63;
      int pos = atomicAdd(&lcur[ld], 1);
      float norm = dis[s] * ldis[ld];
      erec[b * CAP + pos] = make_int2(s, __float_as_int(norm));
    }
  }
}

// ---------------- GEMM: xwb = bf16(x @ W1) ----------------
// Block 256 -> 32 rows x 128 cols, thread = 4 rows x 4 cols. Row = 64 uints.
__global__ __launch_bounds__(256) void gemm_xw(const float* __restrict__ x,
                                               const float* __restrict__ Wg,
                                               unsigned int* __restrict__ xwb) {
  __shared__ float Wl[32 * 128];
  __shared__ float Xlt[32 * 36];
  int t = threadIdx.x;
  int r0 = blockIdx.x * 32;        // 100000 = 32 * 3125 exactly
  int tx = t & 31, ty = t >> 5;
  float acc[4][4] = {};

  for (int kb = 0; kb < 4; ++kb) {
    __syncthreads();
#pragma unroll
    for (int i = 0; i < 4; ++i) {
      int f = (i * 256 + t) * 4;
      *(float4*)&Wl[f] = *(const float4*)&Wg[kb * 32 * 128 + f];
    }
    {
      int row = t >> 3, kk = (t & 7) * 4;
      float4 v = *(const float4*)&x[(r0 + row) * 128 + kb * 32 + kk];
      Xlt[(kk + 0) * 36 + row] = v.x;
      Xlt[(kk + 1) * 36 + row] = v.y;
      Xlt[(kk + 2) * 36 + row] = v.z;
      Xlt[(kk + 3) * 36 + row] = v.w;
    }
    __syncthreads();
#pragma unroll
    for (int k = 0; k < 32; ++k) {
      float4 wv = *(float4*)&Wl[k * 128 + tx * 4];
      float4 xv = *(float4*)&Xlt[k * 36 + ty * 4];
      float xr[4] = {xv.x, xv.y, xv.z, xv.w};
#pragma unroll
      for (int i = 0; i < 4; ++i) {
        acc[i][0] += xr[i] * wv.x;
        acc[i][1] += xr[i] * wv.y;
        acc[i][2] += xr[i] * wv.z;
        acc[i][3] += xr[i] * wv.w;
      }
    }
  }
#pragma unroll
  for (int i = 0; i < 4; ++i) {
    unsigned lo = ((unsigned)f2bf(acc[i][1]) << 16) | f2bf(acc[i][0]);
    unsigned hi = ((unsigned)f2bf(acc[i][3]) << 16) | f2bf(acc[i][2]);
    int row = r0 + ty * 4 + i;
    *(uint2*)&xwb[row * 64 + tx * 2] = make_uint2(lo, hi);
  }
}

// ---------------- Layer-1 aggregation (wave per dst) fused with (h @ W2) ----------
// 4 edges per load step: quarter q = lane>>4 picks the edge, sub = lane&15 owns
// 8 channels (uint4 = 16B). Full iterations are predication-free; tail predicated.
__global__ __launch_bounds__(256) void agg1_kernel(const unsigned int* __restrict__ xwb,
                                                   const float* __restrict__ b1,
                                                   const float* __restrict__ W2,
                                                   const float* __restrict__ dis,
                                                   const int* __restrict__ row_start,
                                                   const int* __restrict__ counts,
                                                   const int2* __restrict__ erec,
                                                   float* __restrict__ hw) {
  int wid = blockIdx.x * 4 + (threadIdx.x >> 6);
  if (wid >= N_NODES) return;
  int lane = threadIdx.x & 63;
  int q = lane >> 4;                      // edge quarter 0..3
  int sub = lane & 15;                    // channel group: 8 ch = 16B
  int c = sub * 8;
  int start = row_start[wid];
  int cnt = counts[wid];
  const uint4* xw4 = (const uint4*)xwb;   // row = node*16 uint4 (256B/row)

  float a0 = 0.f, a1 = 0.f, a2 = 0.f, a3 = 0.f;
  float a4 = 0.f, a5 = 0.f, a6 = 0.f, a7 = 0.f;

  int full = cnt & ~15;
  for (int i = 0; i < full; i += 16) {
#pragma unroll
    for (int k = 0; k < 4; ++k) {
      int2 rec = erec[start + i + 4 * k + q];
      float n = __int_as_float(rec.y);
      uint4 g = xw4[rec.x * 16 + sub];
      a0 += bf_lo(g.x) * n; a1 += bf_hi(g.x) * n;
      a2 += bf_lo(g.y) * n; a3 += bf_hi(g.y) * n;
      a4 += bf_lo(g.z) * n; a5 += bf_hi(g.z) * n;
      a6 += bf_lo(g.w) * n; a7 += bf_hi(g.w) * n;
    }
  }
  if (full < cnt) {  // predicated tail (uniform branch per wave)
#pragma unroll
    for (int k = 0; k < 4; ++k) {
      int ei = full + 4 * k + q;
      bool valid = ei < cnt;
      int2 rec = erec[valid ? (start + ei) : start];
      float n = valid ? __int_as_float(rec.y) : 0.0f;
      uint4 g = xw4[rec.x * 16 + sub];
      a0 += bf_lo(g.x) * n; a1 += bf_hi(g.x) * n;
      a2 += bf_lo(g.y) * n; a3 += bf_hi(g.y) * n;
      a4 += bf_lo(g.z) * n; a5 += bf_hi(g.z) * n;
      a6 += bf_lo(g.w) * n; a7 += bf_hi(g.w) * n;
    }
  }
  // combine the four edge-quarters (lanes sub, sub+16, sub+32, sub+48 share channels)
  a0 += __shfl_xor(a0, 16); a1 += __shfl_xor(a1, 16);
  a2 += __shfl_xor(a2, 16); a3 += __shfl_xor(a3, 16);
  a4 += __shfl_xor(a4, 16); a5 += __shfl_xor(a5, 16);
  a6 += __shfl_xor(a6, 16); a7 += __shfl_xor(a7, 16);
  a0 += __shfl_xor(a0, 32); a1 += __shfl_xor(a1, 32);
  a2 += __shfl_xor(a2, 32); a3 += __shfl_xor(a3, 32);
  a4 += __shfl_xor(a4, 32); a5 += __shfl_xor(a5, 32);
  a6 += __shfl_xor(a6, 32); a7 += __shfl_xor(a7, 32);

  float disw = dis[wid];
  float dsq = disw * disw;
  uint4 gs = xw4[wid * 16 + sub];
  float4 bv0 = *(const float4*)&b1[c];
  float4 bv1 = *(const float4*)&b1[c + 4];
  a0 += bf_lo(gs.x) * dsq + bv0.x;
  a1 += bf_hi(gs.x) * dsq + bv0.y;
  a2 += bf_lo(gs.y) * dsq + bv0.z;
  a3 += bf_hi(gs.y) * dsq + bv0.w;
  a4 += bf_lo(gs.z) * dsq + bv1.x;
  a5 += bf_hi(gs.z) * dsq + bv1.y;
  a6 += bf_lo(gs.w) * dsq + bv1.z;
  a7 += bf_hi(gs.w) * dsq + bv1.w;
  a0 = fmaxf(a0, 0.f); a1 = fmaxf(a1, 0.f);
  a2 = fmaxf(a2, 0.f); a3 = fmaxf(a3, 0.f);
  a4 = fmaxf(a4, 0.f); a5 = fmaxf(a5, 0.f);
  a6 = fmaxf(a6, 0.f); a7 = fmaxf(a7, 0.f);

  // project 8 channels -> 2 outputs: W2 rows c..c+7 = 16 consecutive floats
  float4 wA = *(const float4*)&W2[c * 2];
  float4 wB = *(const float4*)&W2[c * 2 + 4];
  float4 wC = *(const float4*)&W2[c * 2 + 8];
  float4 wD = *(const float4*)&W2[c * 2 + 12];
  float p0 = a0 * wA.x + a1 * wA.z + a2 * wB.x + a3 * wB.z +
             a4 * wC.x + a5 * wC.z + a6 * wD.x + a7 * wD.z;
  float p1 = a0 * wA.y + a1 * wA.w + a2 * wB.y + a3 * wB.w +
             a4 * wC.y + a5 * wC.w + a6 * wD.y + a7 * wD.w;
#pragma unroll
  for (int off = 8; off >= 1; off >>= 1) {
    p0 += __shfl_xor(p0, off);
    p1 += __shfl_xor(p1, off);
  }
  if (lane == 0) *(float2*)&hw[wid * 2] = make_float2(p0, p1);
}

// ---------------- Layer-2 aggregation: 4 nodes per wave (16 lanes each) ----------
__global__ __launch_bounds__(256) void agg2_kernel(const float* __restrict__ hw,
                                                   const float* __restrict__ b2,
                                                   const float* __restrict__ dis,
                                                   const int* __restrict__ row_start,
                                                   const int* __restrict__ counts,
                                                   const int2* __restrict__ erec,
                                                   float* __restrict__ out) {
  int tid = threadIdx.x;
  int wid = blockIdx.x * 16 + (tid >> 4);  // node per 16-lane group
  if (wid >= N_NODES) return;
  int sub = tid & 15;
  int start = row_start[wid];
  int cnt = counts[wid];
  float a0 = 0.f, a1 = 0.f;
  for (int i = sub; i < cnt; i += 16) {
    int2 rec = erec[start + i];
    float n = __int_as_float(rec.y);
    float2 v = *(const float2*)&hw[rec.x * 2];
    a0 += v.x * n;
    a1 += v.y * n;
  }
#pragma unroll
  for (int off = 8; off >= 1; off >>= 1) {
    a0 += __shfl_xor(a0, off);
    a1 += __shfl_xor(a1, off);
  }
  if (sub == 0) {
    float disw = dis[wid];
    float dsq = disw * disw;
    float2 vd = *(const float2*)&hw[wid * 2];
    out[wid * 2 + 0] = a0 + vd.x * dsq + b2[0];
    out[wid * 2 + 1] = a1 + vd.y * dsq + b2[1];
  }
}

// ---------------- launch ----------------

extern "C" void kernel_launch(void* const* d_in, const int* in_sizes, int n_in,
                              void* d_out, int out_size, void* d_ws, size_t ws_size,
                              hipStream_t stream) {
  const float* x  = (const float*)d_in[0];
  const int*   ei = (const int*)d_in[1];
  const float* W1 = (const float*)d_in[2];
  const float* b1 = (const float*)d_in[3];
  const float* W2 = (const float*)d_in[4];
  const float* b2 = (const float*)d_in[5];
  float* out = (float*)d_out;

  const int* src = ei;            // edge_index[0]
  const int* dst = ei + N_EDGES;  // edge_index[1]

  char* ws = (char*)d_ws;
  size_t off = 0;
  auto walloc = [&](size_t bytes) -> void* {
    void* p = ws + off;
    off += (bytes + 255) & ~(size_t)255;
    return p;
  };
  unsigned int* xwb = (unsigned int*)walloc((size_t)N_NODES * 128 * 2);     // 25.6 MB bf16
  int*   cursor     = (int*)walloc((size_t)NB * NSUB * CSTRIDE * 4);        // 1.6 MB padded
  int*   eraw       = (int*)walloc((size_t)NB * NSUB * SCAP * 4);           // 12.8 MB
  int2*  erec       = (int2*)walloc((size_t)NB * CAP * 8);                  // 25.6 MB
  int*   row_start  = (int*)walloc((size_t)N_NODES * 4);
  int*   counts     = (int*)walloc((size_t)N_NODES * 4);
  float* dis        = (float*)walloc((size_t)N_NODES * 4);
  float* hw         = (float*)walloc((size_t)N_NODES * 2 * 4);

  if (off > ws_size) return;  // workspace too small: fail visibly, don't corrupt memory

  hipMemsetAsync(cursor, 0, (size_t)NB * NSUB * CSTRIDE * 4, stream);

  scatter_bucket<<<(N_EDGES + 255) / 256, 256, 0, stream>>>(src, dst, cursor, eraw);
  sort_hist<<<NB, 256, 0, stream>>>(cursor, eraw, row_start, counts, dis);
  sort_place<<<NB, 256, 0, stream>>>(cursor, eraw, counts, dis, erec);
  gemm_xw<<<N_NODES / 32, 256, 0, stream>>>(x, W1, xwb);
  agg1_kernel<<<(N_NODES + 3) / 4, 256, 0, stream>>>(xwb, b1, W2, dis, row_start, counts,
                                                     erec, hw);
  agg2_kernel<<<(N_NODES + 15) / 16, 256, 0, stream>>>(hw, b2, dis, row_start, counts,
                                                       erec, out);
}

// Round 13
// 294.216 us; speedup vs baseline: 5.7380x; 1.0589x over previous
//
#include <hip/hip_runtime.h>

#define N_NODES 100000
#define N_EDGES 1600000
#define NB 1563            // ceil(100000/64) buckets of 64 dst nodes
#define NSUB 8             // per-XCD sub-buckets (real XCC_ID)
#define SCAP 256           // capacity per (bucket, sub): mean 128, +11 sigma
#define CAP 2048           // per-bucket total = NSUB * SCAP
#define CSTRIDE 32         // cursor padding: 1 cursor per 128B line
// IN=128, HID=128, OUT=2

__device__ __forceinline__ int clamp_idx(int v) {
  return v < 0 ? 0 : (v >= N_NODES ? N_NODES - 1 : v);
}

__device__ __forceinline__ unsigned short f2bf(float f) {
  unsigned u = __float_as_uint(f);
  unsigned r = ((u >> 16) & 1u) + 0x7fffu;  // round-to-nearest-even
  return (unsigned short)((u + r) >> 16);
}
__device__ __forceinline__ float bf_lo(unsigned u) { return __uint_as_float(u << 16); }
__device__ __forceinline__ float bf_hi(unsigned u) { return __uint_as_float(u & 0xffff0000u); }

// ---------------- bucketed scatter: real-XCD partition + padded cursors ----------------
__global__ __launch_bounds__(256) void scatter_bucket(const int* __restrict__ src,
                                                      const int* __restrict__ dst,
                                                      int* __restrict__ cursor,
                                                      int* __restrict__ eraw) {
  unsigned xcc;
  asm volatile("s_getreg_b32 %0, hwreg(HW_REG_XCC_ID)" : "=s"(xcc));
  int sub = (int)(xcc & (NSUB - 1));
  int e = blockIdx.x * 256 + threadIdx.x;
  if (e < N_EDGES) {
    int s = clamp_idx(src[e]), d = clamp_idx(dst[e]);
    int b = d >> 6;
    int cell = sub * NB + b;
    int pos = atomicAdd(&cursor[cell * CSTRIDE], 1);
    if (pos < SCAP) eraw[cell * SCAP + pos] = s | ((d & 63) << 20);
  }
}

// ---------------- single-pass bucket sort: LDS-staged hist + scan + place ------------
// Emits node-sorted 4B records, counts, row_start, dis. One global read, one write.
__global__ __launch_bounds__(256) void bucket_sort(const int* __restrict__ cursor,
                                                   const int* __restrict__ eraw,
                                                   int* __restrict__ esrt,
                                                   int* __restrict__ row_start,
                                                   int* __restrict__ counts,
                                                   float* __restrict__ dis) {
  __shared__ int recs[NSUB * SCAP];  // 8 KB staged records
  __shared__ int hist[64];
  __shared__ int lcur[64];
  __shared__ int scnt[NSUB];
  int b = blockIdx.x;
  int t = threadIdx.x;
  if (t < NSUB) {
    int c = cursor[(t * NB + b) * CSTRIDE];
    scnt[t] = c > SCAP ? SCAP : c;
  }
  if (t < 64) hist[t] = 0;
  __syncthreads();
  for (int idx = t; idx < NSUB * SCAP; idx += 256) {
    int sub = idx >> 8;          // SCAP == 256
    int i = idx & (SCAP - 1);
    if (i < scnt[sub]) {
      int r = eraw[(sub * NB + b) * SCAP + i];
      recs[idx] = r;
      atomicAdd(&hist[(r >> 20) & 63], 1);
    }
  }
  __syncthreads();
  if (t < 64) {  // wave 0: 64-wide exclusive scan via shfl
    int v = hist[t];
    int x = v;
#pragma unroll
    for (int dlt = 1; dlt < 64; dlt <<= 1) {
      int y = __shfl_up(x, dlt);
      if (t >= dlt) x += y;
    }
    int ex = x - v;  // exclusive prefix
    lcur[t] = ex;
    int n = b * 64 + t;
    if (n < N_NODES) {
      row_start[n] = b * CAP + ex;
      counts[n] = v;
      dis[n] = rsqrtf((float)v + 1.0f);
    }
  }
  __syncthreads();
  for (int idx = t; idx < NSUB * SCAP; idx += 256) {
    int sub = idx >> 8;
    int i = idx & (SCAP - 1);
    if (i < scnt[sub]) {
      int r = recs[idx];
      int pos = atomicAdd(&lcur[(r >> 20) & 63], 1);
      esrt[b * CAP + pos] = r;
    }
  }
}

// ---------------- GEMM: xwb = bf16(dis[row] * (x @ W1)) ----------------
// dis pre-scaling makes every downstream edge contribution weight-free.
__global__ __launch_bounds__(256) void gemm_xw(const float* __restrict__ x,
                                               const float* __restrict__ Wg,
                                               const float* __restrict__ dis,
                                               unsigned int* __restrict__ xwb) {
  __shared__ float Wl[32 * 128];
  __shared__ float Xlt[32 * 36];
  int t = threadIdx.x;
  int r0 = blockIdx.x * 32;        // 100000 = 32 * 3125 exactly
  int tx = t & 31, ty = t >> 5;
  float acc[4][4] = {};

  for (int kb = 0; kb < 4; ++kb) {
    __syncthreads();
#pragma unroll
    for (int i = 0; i < 4; ++i) {
      int f = (i * 256 + t) * 4;
      *(float4*)&Wl[f] = *(const float4*)&Wg[kb * 32 * 128 + f];
    }
    {
      int row = t >> 3, kk = (t & 7) * 4;
      float4 v = *(const float4*)&x[(r0 + row) * 128 + kb * 32 + kk];
      Xlt[(kk + 0) * 36 + row] = v.x;
      Xlt[(kk + 1) * 36 + row] = v.y;
      Xlt[(kk + 2) * 36 + row] = v.z;
      Xlt[(kk + 3) * 36 + row] = v.w;
    }
    __syncthreads();
#pragma unroll
    for (int k = 0; k < 32; ++k) {
      float4 wv = *(float4*)&Wl[k * 128 + tx * 4];
      float4 xv = *(float4*)&Xlt[k * 36 + ty * 4];
      float xr[4] = {xv.x, xv.y, xv.z, xv.w};
#pragma unroll
      for (int i = 0; i < 4; ++i) {
        acc[i][0] += xr[i] * wv.x;
        acc[i][1] += xr[i] * wv.y;
        acc[i][2] += xr[i] * wv.z;
        acc[i][3] += xr[i] * wv.w;
      }
    }
  }
#pragma unroll
  for (int i = 0; i < 4; ++i) {
    int row = r0 + ty * 4 + i;
    float dsc = dis[row];
    unsigned lo = ((unsigned)f2bf(acc[i][1] * dsc) << 16) | f2bf(acc[i][0] * dsc);
    unsigned hi = ((unsigned)f2bf(acc[i][3] * dsc) << 16) | f2bf(acc[i][2] * dsc);
    *(uint2*)&xwb[row * 64 + tx * 2] = make_uint2(lo, hi);
  }
}

// ---------------- Layer-1 aggregation: UNWEIGHTED sum of pre-scaled rows ----------
// h = dis[d]*(sum_edges xwb[s] + xwb[d]) + b1; hws = dis[d]*(relu(h)@W2).
// 4 edges per step (quarter q), 8 ch per lane (uint4). Full iters: pure unpack+add.
__global__ __launch_bounds__(256) void agg1_kernel(const unsigned int* __restrict__ xwb,
                                                   const float* __restrict__ b1,
                                                   const float* __restrict__ W2,
                                                   const float* __restrict__ dis,
                                                   const int* __restrict__ row_start,
                                                   const int* __restrict__ counts,
                                                   const int* __restrict__ esrt,
                                                   float* __restrict__ hws) {
  int wid = blockIdx.x * 4 + (threadIdx.x >> 6);
  if (wid >= N_NODES) return;
  int lane = threadIdx.x & 63;
  int q = lane >> 4;                      // edge quarter 0..3
  int sub = lane & 15;                    // channel group: 8 ch = 16B
  int c = sub * 8;
  int start = row_start[wid];
  int cnt = counts[wid];
  const uint4* xw4 = (const uint4*)xwb;   // row = node*16 uint4 (256B/row)

  float a0 = 0.f, a1 = 0.f, a2 = 0.f, a3 = 0.f;
  float a4 = 0.f, a5 = 0.f, a6 = 0.f, a7 = 0.f;

  int full = cnt & ~15;
  for (int i = 0; i < full; i += 16) {
#pragma unroll
    for (int k = 0; k < 4; ++k) {
      int r = esrt[start + i + 4 * k + q];
      uint4 g = xw4[(r & 0xFFFFF) * 16 + sub];
      a0 += bf_lo(g.x); a1 += bf_hi(g.x);
      a2 += bf_lo(g.y); a3 += bf_hi(g.y);
      a4 += bf_lo(g.z); a5 += bf_hi(g.z);
      a6 += bf_lo(g.w); a7 += bf_hi(g.w);
    }
  }
  if (full < cnt) {  // predicated tail (uniform branch per wave)
#pragma unroll
    for (int k = 0; k < 4; ++k) {
      int ei = full + 4 * k + q;
      bool valid = ei < cnt;
      int r = esrt[valid ? (start + ei) : start];
      float n = valid ? 1.0f : 0.0f;
      uint4 g = xw4[(r & 0xFFFFF) * 16 + sub];
      a0 += bf_lo(g.x) * n; a1 += bf_hi(g.x) * n;
      a2 += bf_lo(g.y) * n; a3 += bf_hi(g.y) * n;
      a4 += bf_lo(g.z) * n; a5 += bf_hi(g.z) * n;
      a6 += bf_lo(g.w) * n; a7 += bf_hi(g.w) * n;
    }
  }
  // combine the four edge-quarters
  a0 += __shfl_xor(a0, 16); a1 += __shfl_xor(a1, 16);
  a2 += __shfl_xor(a2, 16); a3 += __shfl_xor(a3, 16);
  a4 += __shfl_xor(a4, 16); a5 += __shfl_xor(a5, 16);
  a6 += __shfl_xor(a6, 16); a7 += __shfl_xor(a7, 16);
  a0 += __shfl_xor(a0, 32); a1 += __shfl_xor(a1, 32);
  a2 += __shfl_xor(a2, 32); a3 += __shfl_xor(a3, 32);
  a4 += __shfl_xor(a4, 32); a5 += __shfl_xor(a5, 32);
  a6 += __shfl_xor(a6, 32); a7 += __shfl_xor(a7, 32);

  // self-loop joins the unweighted sum; then h = dis*sum + b1, relu
  float disw = dis[wid];
  uint4 gs = xw4[wid * 16 + sub];
  a0 += bf_lo(gs.x); a1 += bf_hi(gs.x);
  a2 += bf_lo(gs.y); a3 += bf_hi(gs.y);
  a4 += bf_lo(gs.z); a5 += bf_hi(gs.z);
  a6 += bf_lo(gs.w); a7 += bf_hi(gs.w);
  float4 bv0 = *(const float4*)&b1[c];
  float4 bv1 = *(const float4*)&b1[c + 4];
  a0 = fmaxf(fmaf(a0, disw, bv0.x), 0.f);
  a1 = fmaxf(fmaf(a1, disw, bv0.y), 0.f);
  a2 = fmaxf(fmaf(a2, disw, bv0.z), 0.f);
  a3 = fmaxf(fmaf(a3, disw, bv0.w), 0.f);
  a4 = fmaxf(fmaf(a4, disw, bv1.x), 0.f);
  a5 = fmaxf(fmaf(a5, disw, bv1.y), 0.f);
  a6 = fmaxf(fmaf(a6, disw, bv1.z), 0.f);
  a7 = fmaxf(fmaf(a7, disw, bv1.w), 0.f);

  // project 8 channels -> 2 outputs, then pre-scale by dis for layer 2
  float4 wA = *(const float4*)&W2[c * 2];
  float4 wB = *(const float4*)&W2[c * 2 + 4];
  float4 wC = *(const float4*)&W2[c * 2 + 8];
  float4 wD = *(const float4*)&W2[c * 2 + 12];
  float p0 = a0 * wA.x + a1 * wA.z + a2 * wB.x + a3 * wB.z +
             a4 * wC.x + a5 * wC.z + a6 * wD.x + a7 * wD.z;
  float p1 = a0 * wA.y + a1 * wA.w + a2 * wB.y + a3 * wB.w +
             a4 * wC.y + a5 * wC.w + a6 * wD.y + a7 * wD.w;
#pragma unroll
  for (int off = 8; off >= 1; off >>= 1) {
    p0 += __shfl_xor(p0, off);
    p1 += __shfl_xor(p1, off);
  }
  if (lane == 0) *(float2*)&hws[wid * 2] = make_float2(p0 * disw, p1 * disw);
}

// ---------------- Layer-2 aggregation: unweighted sum of pre-scaled hws ----------
__global__ __launch_bounds__(256) void agg2_kernel(const float* __restrict__ hws,
                                                   const float* __restrict__ b2,
                                                   const float* __restrict__ dis,
                                                   const int* __restrict__ row_start,
                                                   const int* __restrict__ counts,
                                                   const int* __restrict__ esrt,
                                                   float* __restrict__ out) {
  int tid = threadIdx.x;
  int wid = blockIdx.x * 16 + (tid >> 4);  // node per 16-lane group
  if (wid >= N_NODES) return;
  int sub = tid & 15;
  int start = row_start[wid];
  int cnt = counts[wid];
  float a0 = 0.f, a1 = 0.f;
  for (int i = sub; i < cnt; i += 16) {
    int r = esrt[start + i];
    float2 v = *(const float2*)&hws[(r & 0xFFFFF) * 2];
    a0 += v.x;
    a1 += v.y;
  }
#pragma unroll
  for (int off = 8; off >= 1; off >>= 1) {
    a0 += __shfl_xor(a0, off);
    a1 += __shfl_xor(a1, off);
  }
  if (sub == 0) {
    float disw = dis[wid];
    float2 vd = *(const float2*)&hws[wid * 2];
    out[wid * 2 + 0] = fmaf(a0 + vd.x, disw, b2[0]);
    out[wid * 2 + 1] = fmaf(a1 + vd.y, disw, b2[1]);
  }
}

// ---------------- launch ----------------

extern "C" void kernel_launch(void* const* d_in, const int* in_sizes, int n_in,
                              void* d_out, int out_size, void* d_ws, size_t ws_size,
                              hipStream_t stream) {
  const float* x  = (const float*)d_in[0];
  const int*   ei = (const int*)d_in[1];
  const float* W1 = (const float*)d_in[2];
  const float* b1 = (const float*)d_in[3];
  const float* W2 = (const float*)d_in[4];
  const float* b2 = (const float*)d_in[5];
  float* out = (float*)d_out;

  const int* src = ei;            // edge_index[0]
  const int* dst = ei + N_EDGES;  // edge_index[1]

  char* ws = (char*)d_ws;
  size_t off = 0;
  auto walloc = [&](size_t bytes) -> void* {
    void* p = ws + off;
    off += (bytes + 255) & ~(size_t)255;
    return p;
  };
  unsigned int* xwb = (unsigned int*)walloc((size_t)N_NODES * 128 * 2);     // 25.6 MB bf16
  int*   cursor     = (int*)walloc((size_t)NB * NSUB * CSTRIDE * 4);        // 1.6 MB padded
  int*   eraw       = (int*)walloc((size_t)NB * NSUB * SCAP * 4);           // 12.8 MB
  int*   esrt       = (int*)walloc((size_t)NB * CAP * 4);                   // 12.8 MB
  int*   row_start  = (int*)walloc((size_t)N_NODES * 4);
  int*   counts     = (int*)walloc((size_t)N_NODES * 4);
  float* dis        = (float*)walloc((size_t)N_NODES * 4);
  float* hws        = (float*)walloc((size_t)N_NODES * 2 * 4);

  if (off > ws_size) return;  // workspace too small: fail visibly, don't corrupt memory

  hipMemsetAsync(cursor, 0, (size_t)NB * NSUB * CSTRIDE * 4, stream);

  scatter_bucket<<<(N_EDGES + 255) / 256, 256, 0, stream>>>(src, dst, cursor, eraw);
  bucket_sort<<<NB, 256, 0, stream>>>(cursor, eraw, esrt, row_start, counts, dis);
  gemm_xw<<<N_NODES / 32, 256, 0, stream>>>(x, W1, dis, xwb);
  agg1_kernel<<<(N_NODES + 3) / 4, 256, 0, stream>>>(xwb, b1, W2, dis, row_start, counts,
                                                     esrt, hws);
  agg2_kernel<<<(N_NODES + 15) / 16, 256, 0, stream>>>(hws, b2, dis, row_start, counts,
                                                       esrt, out);
}

// Round 14
// 237.393 us; speedup vs baseline: 7.1115x; 1.2394x over previous
//
#include <hip/hip_runtime.h>

#define N_NODES 100000
#define N_EDGES 1600000
#define B_COARSE 196       // coarse buckets: d>>9 -> 512 nodes each (last: 160)
#define NODES_PER_CB 512
#define CAP_C 9216         // records per coarse bucket: mean 8192, +11 sigma
#define EPB 4096           // edges per scatter block (1024 threads x 4)
#define NBLK_SCAT ((N_EDGES + EPB - 1) / EPB)   // 391
// IN=128, HID=128, OUT=2

__device__ __forceinline__ int clamp_idx(int v) {
  return v < 0 ? 0 : (v >= N_NODES ? N_NODES - 1 : v);
}

__device__ __forceinline__ unsigned short f2bf(float f) {
  unsigned u = __float_as_uint(f);
  unsigned r = ((u >> 16) & 1u) + 0x7fffu;  // round-to-nearest-even
  return (unsigned short)((u + r) >> 16);
}
__device__ __forceinline__ float bf_lo(unsigned u) { return __uint_as_float(u << 16); }
__device__ __forceinline__ float bf_hi(unsigned u) { return __uint_as_float(u & 0xffff0000u); }

// ---------------- coarse scatter: block-aggregated, run-coalesced writes ----------------
// Block sorts 4096 edges by coarse bucket in LDS, reserves one contiguous range per
// touched bucket (<=196 global atomics vs 4096), writes runs (~21 recs = 84B).
__global__ __launch_bounds__(1024) void scatter_coarse(const int* __restrict__ src,
                                                       const int* __restrict__ dst,
                                                       int* __restrict__ cursor,
                                                       int* __restrict__ eraw) {
  __shared__ int lhist[B_COARSE];
  __shared__ int lscan[B_COARSE];
  __shared__ int lbase[B_COARSE];
  __shared__ int lrec[EPB];
  __shared__ short lbkt[EPB];
  int tid = threadIdx.x;
  int e0 = blockIdx.x * EPB;
  for (int i = tid; i < B_COARSE; i += 1024) lhist[i] = 0;
  __syncthreads();
  int myrec[4], myb[4], mypos[4];
#pragma unroll
  for (int k = 0; k < 4; ++k) {
    int e = e0 + k * 1024 + tid;
    bool v = e < N_EDGES;
    int s = v ? clamp_idx(src[e]) : 0;
    int d = v ? clamp_idx(dst[e]) : 0;
    int b = d >> 9;
    myrec[k] = s | ((d & 511) << 20);   // 20b src | 9b local dst
    myb[k] = b;
    mypos[k] = v ? atomicAdd(&lhist[b], 1) : -1;
  }
  __syncthreads();
  if (tid < 64) {  // wave 0: chunked exclusive scan of 196 bins
    int carry = 0;
    for (int c = 0; c < B_COARSE; c += 64) {
      int idx = c + tid;
      int v = (idx < B_COARSE) ? lhist[idx] : 0;
      int x = v;
#pragma unroll
      for (int dlt = 1; dlt < 64; dlt <<= 1) {
        int y = __shfl_up(x, dlt);
        if (tid >= dlt) x += y;
      }
      if (idx < B_COARSE) lscan[idx] = carry + x - v;
      carry += __shfl(x, 63);
    }
  }
  __syncthreads();
  if (tid < B_COARSE) {
    int cnt = lhist[tid];
    lbase[tid] = cnt > 0 ? atomicAdd(&cursor[tid], cnt) : 0;
  }
#pragma unroll
  for (int k = 0; k < 4; ++k) {
    if (mypos[k] >= 0) {
      int p = lscan[myb[k]] + mypos[k];
      lrec[p] = myrec[k];
      lbkt[p] = (short)myb[k];
    }
  }
  __syncthreads();
  int tot = lscan[B_COARSE - 1] + lhist[B_COARSE - 1];
  for (int i = tid; i < tot; i += 1024) {
    int b = lbkt[i];
    int p = lbase[b] + (i - lscan[b]);
    if (p < CAP_C) eraw[b * CAP_C + p] = lrec[i];
  }
}

// ---------------- fine sort: one block per coarse bucket -> node-sorted CSR ----------
// LDS hist over 512 nodes, wave-0 scan, LDS-staged place, LINEAR esrt write.
// Emits pure-src records, counts, row_start, dis.
__global__ __launch_bounds__(1024) void bucket_sort(const int* __restrict__ cursor,
                                                    const int* __restrict__ eraw,
                                                    int* __restrict__ esrt,
                                                    int* __restrict__ row_start,
                                                    int* __restrict__ counts,
                                                    float* __restrict__ dis) {
  __shared__ int lhist[NODES_PER_CB];
  __shared__ int lcur[NODES_PER_CB];
  __shared__ int lplaced[CAP_C];   // 36 KB
  int cb = blockIdx.x;
  int tid = threadIdx.x;
  int cnt = cursor[cb];
  cnt = cnt > CAP_C ? CAP_C : cnt;
  const int* base = &eraw[cb * CAP_C];
  for (int i = tid; i < NODES_PER_CB; i += 1024) lhist[i] = 0;
  __syncthreads();
  for (int i = tid; i < cnt; i += 1024) {
    atomicAdd(&lhist[base[i] >> 20], 1);
  }
  __syncthreads();
  if (tid < 64) {  // wave 0: chunked exclusive scan of 512 bins -> lcur
    int carry = 0;
    for (int c = 0; c < NODES_PER_CB; c += 64) {
      int idx = c + tid;
      int v = lhist[idx];
      int x = v;
#pragma unroll
      for (int dlt = 1; dlt < 64; dlt <<= 1) {
        int y = __shfl_up(x, dlt);
        if (tid >= dlt) x += y;
      }
      lcur[idx] = carry + x - v;
      carry += __shfl(x, 63);
    }
  }
  __syncthreads();
  if (tid < NODES_PER_CB) {  // per-node outputs (reads lcur BEFORE it mutates)
    int n = cb * NODES_PER_CB + tid;
    if (n < N_NODES) {
      int v = lhist[tid];
      counts[n] = v;
      row_start[n] = cb * CAP_C + lcur[tid];
      dis[n] = rsqrtf((float)v + 1.0f);
    }
  }
  __syncthreads();
  for (int i = tid; i < cnt; i += 1024) {
    int r = base[i];
    int pos = atomicAdd(&lcur[r >> 20], 1);
    lplaced[pos] = r & 0xFFFFF;   // strip local dst -> pure src
  }
  __syncthreads();
  for (int i = tid; i < cnt; i += 1024) {
    esrt[cb * CAP_C + i] = lplaced[i];   // fully coalesced
  }
}

// ---------------- GEMM: xwb = bf16(dis[row] * (x @ W1)) ----------------
__global__ __launch_bounds__(256) void gemm_xw(const float* __restrict__ x,
                                               const float* __restrict__ Wg,
                                               const float* __restrict__ dis,
                                               unsigned int* __restrict__ xwb) {
  __shared__ float Wl[32 * 128];
  __shared__ float Xlt[32 * 36];
  int t = threadIdx.x;
  int r0 = blockIdx.x * 32;        // 100000 = 32 * 3125 exactly
  int tx = t & 31, ty = t >> 5;
  float acc[4][4] = {};

  for (int kb = 0; kb < 4; ++kb) {
    __syncthreads();
#pragma unroll
    for (int i = 0; i < 4; ++i) {
      int f = (i * 256 + t) * 4;
      *(float4*)&Wl[f] = *(const float4*)&Wg[kb * 32 * 128 + f];
    }
    {
      int row = t >> 3, kk = (t & 7) * 4;
      float4 v = *(const float4*)&x[(r0 + row) * 128 + kb * 32 + kk];
      Xlt[(kk + 0) * 36 + row] = v.x;
      Xlt[(kk + 1) * 36 + row] = v.y;
      Xlt[(kk + 2) * 36 + row] = v.z;
      Xlt[(kk + 3) * 36 + row] = v.w;
    }
    __syncthreads();
#pragma unroll
    for (int k = 0; k < 32; ++k) {
      float4 wv = *(float4*)&Wl[k * 128 + tx * 4];
      float4 xv = *(float4*)&Xlt[k * 36 + ty * 4];
      float xr[4] = {xv.x, xv.y, xv.z, xv.w};
#pragma unroll
      for (int i = 0; i < 4; ++i) {
        acc[i][0] += xr[i] * wv.x;
        acc[i][1] += xr[i] * wv.y;
        acc[i][2] += xr[i] * wv.z;
        acc[i][3] += xr[i] * wv.w;
      }
    }
  }
#pragma unroll
  for (int i = 0; i < 4; ++i) {
    int row = r0 + ty * 4 + i;
    float dsc = dis[row];
    unsigned lo = ((unsigned)f2bf(acc[i][1] * dsc) << 16) | f2bf(acc[i][0] * dsc);
    unsigned hi = ((unsigned)f2bf(acc[i][3] * dsc) << 16) | f2bf(acc[i][2] * dsc);
    *(uint2*)&xwb[row * 64 + tx * 2] = make_uint2(lo, hi);
  }
}

// ---------------- Layer-1 aggregation: unweighted sum of pre-scaled rows ----------
__global__ __launch_bounds__(256) void agg1_kernel(const unsigned int* __restrict__ xwb,
                                                   const float* __restrict__ b1,
                                                   const float* __restrict__ W2,
                                                   const float* __restrict__ dis,
                                                   const int* __restrict__ row_start,
                                                   const int* __restrict__ counts,
                                                   const int* __restrict__ esrt,
                                                   float* __restrict__ hws) {
  int wid = blockIdx.x * 4 + (threadIdx.x >> 6);
  if (wid >= N_NODES) return;
  int lane = threadIdx.x & 63;
  int q = lane >> 4;                      // edge quarter 0..3
  int sub = lane & 15;                    // channel group: 8 ch = 16B
  int c = sub * 8;
  int start = row_start[wid];
  int cnt = counts[wid];
  const uint4* xw4 = (const uint4*)xwb;   // row = node*16 uint4 (256B/row)

  float a0 = 0.f, a1 = 0.f, a2 = 0.f, a3 = 0.f;
  float a4 = 0.f, a5 = 0.f, a6 = 0.f, a7 = 0.f;

  int full = cnt & ~15;
  for (int i = 0; i < full; i += 16) {
#pragma unroll
    for (int k = 0; k < 4; ++k) {
      int s = esrt[start + i + 4 * k + q];
      uint4 g = xw4[s * 16 + sub];
      a0 += bf_lo(g.x); a1 += bf_hi(g.x);
      a2 += bf_lo(g.y); a3 += bf_hi(g.y);
      a4 += bf_lo(g.z); a5 += bf_hi(g.z);
      a6 += bf_lo(g.w); a7 += bf_hi(g.w);
    }
  }
  if (full < cnt) {  // predicated tail (uniform branch per wave)
#pragma unroll
    for (int k = 0; k < 4; ++k) {
      int ei = full + 4 * k + q;
      bool valid = ei < cnt;
      int s = esrt[valid ? (start + ei) : start];
      float n = valid ? 1.0f : 0.0f;
      uint4 g = xw4[s * 16 + sub];
      a0 += bf_lo(g.x) * n; a1 += bf_hi(g.x) * n;
      a2 += bf_lo(g.y) * n; a3 += bf_hi(g.y) * n;
      a4 += bf_lo(g.z) * n; a5 += bf_hi(g.z) * n;
      a6 += bf_lo(g.w) * n; a7 += bf_hi(g.w) * n;
    }
  }
  // combine the four edge-quarters
  a0 += __shfl_xor(a0, 16); a1 += __shfl_xor(a1, 16);
  a2 += __shfl_xor(a2, 16); a3 += __shfl_xor(a3, 16);
  a4 += __shfl_xor(a4, 16); a5 += __shfl_xor(a5, 16);
  a6 += __shfl_xor(a6, 16); a7 += __shfl_xor(a7, 16);
  a0 += __shfl_xor(a0, 32); a1 += __shfl_xor(a1, 32);
  a2 += __shfl_xor(a2, 32); a3 += __shfl_xor(a3, 32);
  a4 += __shfl_xor(a4, 32); a5 += __shfl_xor(a5, 32);
  a6 += __shfl_xor(a6, 32); a7 += __shfl_xor(a7, 32);

  // self-loop joins the unweighted sum; then h = dis*sum + b1, relu
  float disw = dis[wid];
  uint4 gs = xw4[wid * 16 + sub];
  a0 += bf_lo(gs.x); a1 += bf_hi(gs.x);
  a2 += bf_lo(gs.y); a3 += bf_hi(gs.y);
  a4 += bf_lo(gs.z); a5 += bf_hi(gs.z);
  a6 += bf_lo(gs.w); a7 += bf_hi(gs.w);
  float4 bv0 = *(const float4*)&b1[c];
  float4 bv1 = *(const float4*)&b1[c + 4];
  a0 = fmaxf(fmaf(a0, disw, bv0.x), 0.f);
  a1 = fmaxf(fmaf(a1, disw, bv0.y), 0.f);
  a2 = fmaxf(fmaf(a2, disw, bv0.z), 0.f);
  a3 = fmaxf(fmaf(a3, disw, bv0.w), 0.f);
  a4 = fmaxf(fmaf(a4, disw, bv1.x), 0.f);
  a5 = fmaxf(fmaf(a5, disw, bv1.y), 0.f);
  a6 = fmaxf(fmaf(a6, disw, bv1.z), 0.f);
  a7 = fmaxf(fmaf(a7, disw, bv1.w), 0.f);

  // project 8 channels -> 2 outputs, then pre-scale by dis for layer 2
  float4 wA = *(const float4*)&W2[c * 2];
  float4 wB = *(const float4*)&W2[c * 2 + 4];
  float4 wC = *(const float4*)&W2[c * 2 + 8];
  float4 wD = *(const float4*)&W2[c * 2 + 12];
  float p0 = a0 * wA.x + a1 * wA.z + a2 * wB.x + a3 * wB.z +
             a4 * wC.x + a5 * wC.z + a6 * wD.x + a7 * wD.z;
  float p1 = a0 * wA.y + a1 * wA.w + a2 * wB.y + a3 * wB.w +
             a4 * wC.y + a5 * wC.w + a6 * wD.y + a7 * wD.w;
#pragma unroll
  for (int off = 8; off >= 1; off >>= 1) {
    p0 += __shfl_xor(p0, off);
    p1 += __shfl_xor(p1, off);
  }
  if (lane == 0) *(float2*)&hws[wid * 2] = make_float2(p0 * disw, p1 * disw);
}

// ---------------- Layer-2 aggregation: unweighted sum of pre-scaled hws ----------
__global__ __launch_bounds__(256) void agg2_kernel(const float* __restrict__ hws,
                                                   const float* __restrict__ b2,
                                                   const float* __restrict__ dis,
                                                   const int* __restrict__ row_start,
                                                   const int* __restrict__ counts,
                                                   const int* __restrict__ esrt,
                                                   float* __restrict__ out) {
  int tid = threadIdx.x;
  int wid = blockIdx.x * 16 + (tid >> 4);  // node per 16-lane group
  if (wid >= N_NODES) return;
  int sub = tid & 15;
  int start = row_start[wid];
  int cnt = counts[wid];
  float a0 = 0.f, a1 = 0.f;
  for (int i = sub; i < cnt; i += 16) {
    int s = esrt[start + i];
    float2 v = *(const float2*)&hws[s * 2];
    a0 += v.x;
    a1 += v.y;
  }
#pragma unroll
  for (int off = 8; off >= 1; off >>= 1) {
    a0 += __shfl_xor(a0, off);
    a1 += __shfl_xor(a1, off);
  }
  if (sub == 0) {
    float disw = dis[wid];
    float2 vd = *(const float2*)&hws[wid * 2];
    out[wid * 2 + 0] = fmaf(a0 + vd.x, disw, b2[0]);
    out[wid * 2 + 1] = fmaf(a1 + vd.y, disw, b2[1]);
  }
}

// ---------------- launch ----------------

extern "C" void kernel_launch(void* const* d_in, const int* in_sizes, int n_in,
                              void* d_out, int out_size, void* d_ws, size_t ws_size,
                              hipStream_t stream) {
  const float* x  = (const float*)d_in[0];
  const int*   ei = (const int*)d_in[1];
  const float* W1 = (const float*)d_in[2];
  const float* b1 = (const float*)d_in[3];
  const float* W2 = (const float*)d_in[4];
  const float* b2 = (const float*)d_in[5];
  float* out = (float*)d_out;

  const int* src = ei;            // edge_index[0]
  const int* dst = ei + N_EDGES;  // edge_index[1]

  char* ws = (char*)d_ws;
  size_t off = 0;
  auto walloc = [&](size_t bytes) -> void* {
    void* p = ws + off;
    off += (bytes + 255) & ~(size_t)255;
    return p;
  };
  unsigned int* xwb = (unsigned int*)walloc((size_t)N_NODES * 128 * 2);   // 25.6 MB bf16
  int*   cursor     = (int*)walloc((size_t)B_COARSE * 4);
  int*   eraw       = (int*)walloc((size_t)B_COARSE * CAP_C * 4);         // 7.2 MB
  int*   esrt       = (int*)walloc((size_t)B_COARSE * CAP_C * 4);         // 7.2 MB
  int*   row_start  = (int*)walloc((size_t)N_NODES * 4);
  int*   counts     = (int*)walloc((size_t)N_NODES * 4);
  float* dis        = (float*)walloc((size_t)N_NODES * 4);
  float* hws        = (float*)walloc((size_t)N_NODES * 2 * 4);

  if (off > ws_size) return;  // workspace too small: fail visibly, don't corrupt memory

  hipMemsetAsync(cursor, 0, (size_t)B_COARSE * 4, stream);

  scatter_coarse<<<NBLK_SCAT, 1024, 0, stream>>>(src, dst, cursor, eraw);
  bucket_sort<<<B_COARSE, 1024, 0, stream>>>(cursor, eraw, esrt, row_start, counts, dis);
  gemm_xw<<<N_NODES / 32, 256, 0, stream>>>(x, W1, dis, xwb);
  agg1_kernel<<<(N_NODES + 3) / 4, 256, 0, stream>>>(xwb, b1, W2, dis, row_start, counts,
                                                     esrt, hws);
  agg2_kernel<<<(N_NODES + 15) / 16, 256, 0, stream>>>(hws, b2, dis, row_start, counts,
                                                       esrt, out);
}

// Round 15
// 209.835 us; speedup vs baseline: 8.0455x; 1.1313x over previous
//
#include <hip/hip_runtime.h>

#define N_NODES 100000
#define N_EDGES 1600000
#define B_COARSE 196       // coarse buckets: d>>9 -> 512 nodes each (last: 160)
#define NODES_PER_CB 512
#define CAP_C 9216         // records per coarse bucket: mean 8192, +11 sigma
#define EPB 4096           // edges per scatter block (1024 threads x 4)
#define NBLK_SCAT ((N_EDGES + EPB - 1) / EPB)   // 391
// IN=128, HID=128, OUT=2

typedef __attribute__((ext_vector_type(8))) short bf16x8;
typedef __attribute__((ext_vector_type(4))) float f32x4;

__device__ __forceinline__ int clamp_idx(int v) {
  return v < 0 ? 0 : (v >= N_NODES ? N_NODES - 1 : v);
}

__device__ __forceinline__ unsigned short f2bf(float f) {
  unsigned u = __float_as_uint(f);
  unsigned r = ((u >> 16) & 1u) + 0x7fffu;  // round-to-nearest-even
  return (unsigned short)((u + r) >> 16);
}
__device__ __forceinline__ float bf_lo(unsigned u) { return __uint_as_float(u << 16); }
__device__ __forceinline__ float bf_hi(unsigned u) { return __uint_as_float(u & 0xffff0000u); }

// ---------------- coarse scatter: block-aggregated, run-coalesced writes ----------------
__global__ __launch_bounds__(1024) void scatter_coarse(const int* __restrict__ src,
                                                       const int* __restrict__ dst,
                                                       int* __restrict__ cursor,
                                                       int* __restrict__ eraw) {
  __shared__ int lhist[B_COARSE];
  __shared__ int lscan[B_COARSE];
  __shared__ int lbase[B_COARSE];
  __shared__ int lrec[EPB];
  __shared__ short lbkt[EPB];
  int tid = threadIdx.x;
  int e0 = blockIdx.x * EPB;
  for (int i = tid; i < B_COARSE; i += 1024) lhist[i] = 0;
  __syncthreads();
  int myrec[4], myb[4], mypos[4];
#pragma unroll
  for (int k = 0; k < 4; ++k) {
    int e = e0 + k * 1024 + tid;
    bool v = e < N_EDGES;
    int s = v ? clamp_idx(src[e]) : 0;
    int d = v ? clamp_idx(dst[e]) : 0;
    int b = d >> 9;
    myrec[k] = s | ((d & 511) << 20);   // 20b src | 9b local dst
    myb[k] = b;
    mypos[k] = v ? atomicAdd(&lhist[b], 1) : -1;
  }
  __syncthreads();
  if (tid < 64) {  // wave 0: chunked exclusive scan of 196 bins
    int carry = 0;
    for (int c = 0; c < B_COARSE; c += 64) {
      int idx = c + tid;
      int v = (idx < B_COARSE) ? lhist[idx] : 0;
      int x = v;
#pragma unroll
      for (int dlt = 1; dlt < 64; dlt <<= 1) {
        int y = __shfl_up(x, dlt);
        if (tid >= dlt) x += y;
      }
      if (idx < B_COARSE) lscan[idx] = carry + x - v;
      carry += __shfl(x, 63);
    }
  }
  __syncthreads();
  if (tid < B_COARSE) {
    int cnt = lhist[tid];
    lbase[tid] = cnt > 0 ? atomicAdd(&cursor[tid], cnt) : 0;
  }
#pragma unroll
  for (int k = 0; k < 4; ++k) {
    if (mypos[k] >= 0) {
      int p = lscan[myb[k]] + mypos[k];
      lrec[p] = myrec[k];
      lbkt[p] = (short)myb[k];
    }
  }
  __syncthreads();
  int tot = lscan[B_COARSE - 1] + lhist[B_COARSE - 1];
  for (int i = tid; i < tot; i += 1024) {
    int b = lbkt[i];
    int p = lbase[b] + (i - lscan[b]);
    if (p < CAP_C) eraw[b * CAP_C + p] = lrec[i];
  }
}

// ---------------- fine sort: one block per coarse bucket -> node-sorted CSR ----------
__global__ __launch_bounds__(1024) void bucket_sort(const int* __restrict__ cursor,
                                                    const int* __restrict__ eraw,
                                                    int* __restrict__ esrt,
                                                    int* __restrict__ row_start,
                                                    int* __restrict__ counts,
                                                    float* __restrict__ dis) {
  __shared__ int lhist[NODES_PER_CB];
  __shared__ int lcur[NODES_PER_CB];
  __shared__ int lplaced[CAP_C];   // 36 KB
  int cb = blockIdx.x;
  int tid = threadIdx.x;
  int cnt = cursor[cb];
  cnt = cnt > CAP_C ? CAP_C : cnt;
  const int* base = &eraw[cb * CAP_C];
  for (int i = tid; i < NODES_PER_CB; i += 1024) lhist[i] = 0;
  __syncthreads();
  for (int i = tid; i < cnt; i += 1024) {
    atomicAdd(&lhist[base[i] >> 20], 1);
  }
  __syncthreads();
  if (tid < 64) {  // wave 0: chunked exclusive scan of 512 bins -> lcur
    int carry = 0;
    for (int c = 0; c < NODES_PER_CB; c += 64) {
      int idx = c + tid;
      int v = lhist[idx];
      int x = v;
#pragma unroll
      for (int dlt = 1; dlt < 64; dlt <<= 1) {
        int y = __shfl_up(x, dlt);
        if (tid >= dlt) x += y;
      }
      lcur[idx] = carry + x - v;
      carry += __shfl(x, 63);
    }
  }
  __syncthreads();
  if (tid < NODES_PER_CB) {  // per-node outputs (reads lcur BEFORE it mutates)
    int n = cb * NODES_PER_CB + tid;
    if (n < N_NODES) {
      int v = lhist[tid];
      counts[n] = v;
      row_start[n] = cb * CAP_C + lcur[tid];
      dis[n] = rsqrtf((float)v + 1.0f);
    }
  }
  __syncthreads();
  for (int i = tid; i < cnt; i += 1024) {
    int r = base[i];
    int pos = atomicAdd(&lcur[r >> 20], 1);
    lplaced[pos] = r & 0xFFFFF;   // strip local dst -> pure src
  }
  __syncthreads();
  for (int i = tid; i < cnt; i += 1024) {
    esrt[cb * CAP_C + i] = lplaced[i];   // fully coalesced
  }
}

// ---------------- W1 -> MFMA B-fragment pre-pack ----------------
// Fragment for mfma_f32_16x16x32_bf16: B[k][n], n = lane&15, k = kt*32 + (lane>>4)*8 + j.
// Layout: w1f[((kt*8 + nt)*64 + lane)*4 ..+4] = 4 uints (8 bf16, j ascending).
__global__ __launch_bounds__(256) void w1frag_kernel(const float* __restrict__ W1,
                                                     unsigned int* __restrict__ w1f) {
  int t = threadIdx.x;
#pragma unroll
  for (int it = 0; it < 8; ++it) {
    int slot = it * 256 + t;        // 0..2047
    int kt = slot >> 9;
    int nt = (slot >> 6) & 7;
    int lane = slot & 63;
    int col = nt * 16 + (lane & 15);
    int kbase = kt * 32 + (lane >> 4) * 8;
    unsigned u[4];
#pragma unroll
    for (int jj = 0; jj < 4; ++jj) {
      float f0 = W1[(kbase + 2 * jj) * 128 + col];
      float f1 = W1[(kbase + 2 * jj + 1) * 128 + col];
      u[jj] = ((unsigned)f2bf(f1) << 16) | f2bf(f0);
    }
    *(uint4*)&w1f[slot * 4] = make_uint4(u[0], u[1], u[2], u[3]);
  }
}

// ---------------- GEMM via MFMA: xwb = bf16(dis[row] * (x @ W1)) ----------------
// Block = 256 threads (4 waves), 64 rows. Wave w: rows w*16..+15, all 128 cols.
// LDS: x tile as bf16, row stride 68 uints (pad de-aliases banks); reused for repack.
__global__ __launch_bounds__(256) void gemm_mfma(const float* __restrict__ x,
                                                 const unsigned int* __restrict__ w1f,
                                                 const float* __restrict__ dis,
                                                 unsigned int* __restrict__ xwb) {
  __shared__ unsigned short Sl[64 * 136];         // 17408 B, aliased below
  unsigned int* Xl = (unsigned int*)Sl;           // staging view: [64 rows][68 uints]
  int t = threadIdx.x;
  int r0 = blockIdx.x * 64;
  int w = t >> 6, lane = t & 63;

  // stage x (fp32 -> bf16): 64 rows x 32 float4; thread handles 8 float4
#pragma unroll
  for (int it = 0; it < 8; ++it) {
    int flat = it * 256 + t;
    int row = flat >> 5;            // 0..63
    int c4 = flat & 31;             // float4 index: k = c4*4
    int grow = r0 + row;
    float4 v = (grow < N_NODES) ? *(const float4*)&x[grow * 128 + c4 * 4]
                                : make_float4(0.f, 0.f, 0.f, 0.f);
    unsigned lo = ((unsigned)f2bf(v.y) << 16) | f2bf(v.x);
    unsigned hi = ((unsigned)f2bf(v.w) << 16) | f2bf(v.z);
    *(uint2*)&Xl[row * 68 + c4 * 2] = make_uint2(lo, hi);
  }
  __syncthreads();

  f32x4 acc[8];
#pragma unroll
  for (int nt = 0; nt < 8; ++nt) acc[nt] = (f32x4){0.f, 0.f, 0.f, 0.f};

  int lrow = (w << 4) + (lane & 15);
#pragma unroll
  for (int kt = 0; kt < 4; ++kt) {
    int cu = (kt * 4 + (lane >> 4)) * 4;          // chunk start in uints (8 k's = 4 uints)
    bf16x8 af = *(const bf16x8*)&Xl[lrow * 68 + cu];
#pragma unroll
    for (int nt = 0; nt < 8; ++nt) {
      bf16x8 bfr = *(const bf16x8*)&w1f[((kt * 8 + nt) * 64 + lane) * 4];
      acc[nt] = __builtin_amdgcn_mfma_f32_16x16x32_bf16(af, bfr, acc[nt], 0, 0, 0);
    }
  }
  __syncthreads();   // staging reads done; reuse LDS for repack

  // epilogue: scale by dis, cvt bf16, write to LDS [64][136] ushort
  float dsc[4];
#pragma unroll
  for (int reg = 0; reg < 4; ++reg) {
    int grow = r0 + (w << 4) + ((lane >> 4) << 2) + reg;
    dsc[reg] = (grow < N_NODES) ? dis[grow] : 0.f;
  }
#pragma unroll
  for (int nt = 0; nt < 8; ++nt) {
#pragma unroll
    for (int reg = 0; reg < 4; ++reg) {
      int lr = (w << 4) + ((lane >> 4) << 2) + reg;
      int col = nt * 16 + (lane & 15);
      Sl[lr * 136 + col] = f2bf(acc[nt][reg] * dsc[reg]);
    }
  }
  __syncthreads();

  // coalesced write-out: 64 rows x 16 uint4
#pragma unroll
  for (int it = 0; it < 4; ++it) {
    int flat = it * 256 + t;
    int row = flat >> 4;            // 0..63
    int c = flat & 15;
    int grow = r0 + row;
    if (grow < N_NODES) {
      uint4 v = *(uint4*)&Xl[row * 68 + c * 4];
      *(uint4*)&xwb[grow * 64 + c * 4] = v;
    }
  }
}

// ---------------- Layer-1 aggregation: unweighted sum of pre-scaled rows ----------
__global__ __launch_bounds__(256) void agg1_kernel(const unsigned int* __restrict__ xwb,
                                                   const float* __restrict__ b1,
                                                   const float* __restrict__ W2,
                                                   const float* __restrict__ dis,
                                                   const int* __restrict__ row_start,
                                                   const int* __restrict__ counts,
                                                   const int* __restrict__ esrt,
                                                   float* __restrict__ hws) {
  int wid = blockIdx.x * 4 + (threadIdx.x >> 6);
  if (wid >= N_NODES) return;
  int lane = threadIdx.x & 63;
  int q = lane >> 4;                      // edge quarter 0..3
  int sub = lane & 15;                    // channel group: 8 ch = 16B
  int c = sub * 8;
  int start = row_start[wid];
  int cnt = counts[wid];
  const uint4* xw4 = (const uint4*)xwb;   // row = node*16 uint4 (256B/row)

  float a0 = 0.f, a1 = 0.f, a2 = 0.f, a3 = 0.f;
  float a4 = 0.f, a5 = 0.f, a6 = 0.f, a7 = 0.f;

  int full = cnt & ~15;
  for (int i = 0; i < full; i += 16) {
#pragma unroll
    for (int k = 0; k < 4; ++k) {
      int s = esrt[start + i + 4 * k + q];
      uint4 g = xw4[s * 16 + sub];
      a0 += bf_lo(g.x); a1 += bf_hi(g.x);
      a2 += bf_lo(g.y); a3 += bf_hi(g.y);
      a4 += bf_lo(g.z); a5 += bf_hi(g.z);
      a6 += bf_lo(g.w); a7 += bf_hi(g.w);
    }
  }
  if (full < cnt) {  // predicated tail (uniform branch per wave)
#pragma unroll
    for (int k = 0; k < 4; ++k) {
      int ei = full + 4 * k + q;
      bool valid = ei < cnt;
      int s = esrt[valid ? (start + ei) : start];
      float n = valid ? 1.0f : 0.0f;
      uint4 g = xw4[s * 16 + sub];
      a0 += bf_lo(g.x) * n; a1 += bf_hi(g.x) * n;
      a2 += bf_lo(g.y) * n; a3 += bf_hi(g.y) * n;
      a4 += bf_lo(g.z) * n; a5 += bf_hi(g.z) * n;
      a6 += bf_lo(g.w) * n; a7 += bf_hi(g.w) * n;
    }
  }
  // combine the four edge-quarters
  a0 += __shfl_xor(a0, 16); a1 += __shfl_xor(a1, 16);
  a2 += __shfl_xor(a2, 16); a3 += __shfl_xor(a3, 16);
  a4 += __shfl_xor(a4, 16); a5 += __shfl_xor(a5, 16);
  a6 += __shfl_xor(a6, 16); a7 += __shfl_xor(a7, 16);
  a0 += __shfl_xor(a0, 32); a1 += __shfl_xor(a1, 32);
  a2 += __shfl_xor(a2, 32); a3 += __shfl_xor(a3, 32);
  a4 += __shfl_xor(a4, 32); a5 += __shfl_xor(a5, 32);
  a6 += __shfl_xor(a6, 32); a7 += __shfl_xor(a7, 32);

  // self-loop joins the unweighted sum; then h = dis*sum + b1, relu
  float disw = dis[wid];
  uint4 gs = xw4[wid * 16 + sub];
  a0 += bf_lo(gs.x); a1 += bf_hi(gs.x);
  a2 += bf_lo(gs.y); a3 += bf_hi(gs.y);
  a4 += bf_lo(gs.z); a5 += bf_hi(gs.z);
  a6 += bf_lo(gs.w); a7 += bf_hi(gs.w);
  float4 bv0 = *(const float4*)&b1[c];
  float4 bv1 = *(const float4*)&b1[c + 4];
  a0 = fmaxf(fmaf(a0, disw, bv0.x), 0.f);
  a1 = fmaxf(fmaf(a1, disw, bv0.y), 0.f);
  a2 = fmaxf(fmaf(a2, disw, bv0.z), 0.f);
  a3 = fmaxf(fmaf(a3, disw, bv0.w), 0.f);
  a4 = fmaxf(fmaf(a4, disw, bv1.x), 0.f);
  a5 = fmaxf(fmaf(a5, disw, bv1.y), 0.f);
  a6 = fmaxf(fmaf(a6, disw, bv1.z), 0.f);
  a7 = fmaxf(fmaf(a7, disw, bv1.w), 0.f);

  // project 8 channels -> 2 outputs, then pre-scale by dis for layer 2
  float4 wA = *(const float4*)&W2[c * 2];
  float4 wB = *(const float4*)&W2[c * 2 + 4];
  float4 wC = *(const float4*)&W2[c * 2 + 8];
  float4 wD = *(const float4*)&W2[c * 2 + 12];
  float p0 = a0 * wA.x + a1 * wA.z + a2 * wB.x + a3 * wB.z +
             a4 * wC.x + a5 * wC.z + a6 * wD.x + a7 * wD.z;
  float p1 = a0 * wA.y + a1 * wA.w + a2 * wB.y + a3 * wB.w +
             a4 * wC.y + a5 * wC.w + a6 * wD.y + a7 * wD.w;
#pragma unroll
  for (int off = 8; off >= 1; off >>= 1) {
    p0 += __shfl_xor(p0, off);
    p1 += __shfl_xor(p1, off);
  }
  if (lane == 0) *(float2*)&hws[wid * 2] = make_float2(p0 * disw, p1 * disw);
}

// ---------------- Layer-2 aggregation: unweighted sum of pre-scaled hws ----------
__global__ __launch_bounds__(256) void agg2_kernel(const float* __restrict__ hws,
                                                   const float* __restrict__ b2,
                                                   const float* __restrict__ dis,
                                                   const int* __restrict__ row_start,
                                                   const int* __restrict__ counts,
                                                   const int* __restrict__ esrt,
                                                   float* __restrict__ out) {
  int tid = threadIdx.x;
  int wid = blockIdx.x * 16 + (tid >> 4);  // node per 16-lane group
  if (wid >= N_NODES) return;
  int sub = tid & 15;
  int start = row_start[wid];
  int cnt = counts[wid];
  float a0 = 0.f, a1 = 0.f;
  for (int i = sub; i < cnt; i += 16) {
    int s = esrt[start + i];
    float2 v = *(const float2*)&hws[s * 2];
    a0 += v.x;
    a1 += v.y;
  }
#pragma unroll
  for (int off = 8; off >= 1; off >>= 1) {
    a0 += __shfl_xor(a0, off);
    a1 += __shfl_xor(a1, off);
  }
  if (sub == 0) {
    float disw = dis[wid];
    float2 vd = *(const float2*)&hws[wid * 2];
    out[wid * 2 + 0] = fmaf(a0 + vd.x, disw, b2[0]);
    out[wid * 2 + 1] = fmaf(a1 + vd.y, disw, b2[1]);
  }
}

// ---------------- launch ----------------

extern "C" void kernel_launch(void* const* d_in, const int* in_sizes, int n_in,
                              void* d_out, int out_size, void* d_ws, size_t ws_size,
                              hipStream_t stream) {
  const float* x  = (const float*)d_in[0];
  const int*   ei = (const int*)d_in[1];
  const float* W1 = (const float*)d_in[2];
  const float* b1 = (const float*)d_in[3];
  const float* W2 = (const float*)d_in[4];
  const float* b2 = (const float*)d_in[5];
  float* out = (float*)d_out;

  const int* src = ei;            // edge_index[0]
  const int* dst = ei + N_EDGES;  // edge_index[1]

  char* ws = (char*)d_ws;
  size_t off = 0;
  auto walloc = [&](size_t bytes) -> void* {
    void* p = ws + off;
    off += (bytes + 255) & ~(size_t)255;
    return p;
  };
  unsigned int* xwb = (unsigned int*)walloc((size_t)N_NODES * 128 * 2);   // 25.6 MB bf16
  int*   cursor     = (int*)walloc((size_t)B_COARSE * 4);
  int*   eraw       = (int*)walloc((size_t)B_COARSE * CAP_C * 4);         // 7.2 MB
  int*   esrt       = (int*)walloc((size_t)B_COARSE * CAP_C * 4);         // 7.2 MB
  int*   row_start  = (int*)walloc((size_t)N_NODES * 4);
  int*   counts     = (int*)walloc((size_t)N_NODES * 4);
  float* dis        = (float*)walloc((size_t)N_NODES * 4);
  float* hws        = (float*)walloc((size_t)N_NODES * 2 * 4);
  unsigned int* w1f = (unsigned int*)walloc((size_t)2048 * 16);           // 32 KB frags

  if (off > ws_size) return;  // workspace too small: fail visibly, don't corrupt memory

  hipMemsetAsync(cursor, 0, (size_t)B_COARSE * 4, stream);

  w1frag_kernel<<<1, 256, 0, stream>>>(W1, w1f);
  scatter_coarse<<<NBLK_SCAT, 1024, 0, stream>>>(src, dst, cursor, eraw);
  bucket_sort<<<B_COARSE, 1024, 0, stream>>>(cursor, eraw, esrt, row_start, counts, dis);
  gemm_mfma<<<(N_NODES + 63) / 64, 256, 0, stream>>>(x, w1f, dis, xwb);
  agg1_kernel<<<(N_NODES + 3) / 4, 256, 0, stream>>>(xwb, b1, W2, dis, row_start, counts,
                                                     esrt, hws);
  agg2_kernel<<<(N_NODES + 15) / 16, 256, 0, stream>>>(hws, b2, dis, row_start, counts,
                                                       esrt, out);
}